// Round 1
// baseline (395.592 us; speedup 1.0000x reference)
//
#include <hip/hip_runtime.h>

__device__ __forceinline__ float lrelu02(float a) { return a > 0.0f ? a : 0.2f * a; }

// -------------------- CSR build --------------------
__global__ void k_deg(const int* __restrict__ ei, int* __restrict__ deg, int E, int N) {
    int e = blockIdx.x * blockDim.x + threadIdx.x;
    if (e < E) {
        atomicAdd(&deg[ei[E + e]], 1);          // dst row of edge_index
    } else if (e < E + N) {
        atomicAdd(&deg[e - E], 1);              // self loop
    }
}

__global__ __launch_bounds__(1024) void k_scan(const int* __restrict__ deg,
                                               int* __restrict__ rowptr, int N) {
    __shared__ int sums[1024];
    int t = threadIdx.x;
    int C = (N + 1023) >> 10;
    int lo = t * C;
    int hi = min(lo + C, N);
    int s = 0;
    for (int i = lo; i < hi; ++i) s += deg[i];
    sums[t] = s;
    __syncthreads();
    for (int off = 1; off < 1024; off <<= 1) {
        int v = (t >= off) ? sums[t - off] : 0;
        __syncthreads();
        sums[t] += v;
        __syncthreads();
    }
    int base = (t == 0) ? 0 : sums[t - 1];
    for (int i = lo; i < hi; ++i) { rowptr[i] = base; base += deg[i]; }
    if (t == 1023) rowptr[N] = sums[1023];
}

__global__ void k_fill(const int* __restrict__ ei, const int* __restrict__ rowptr,
                       int* __restrict__ fillc, int* __restrict__ col, int E, int N) {
    int e = blockIdx.x * blockDim.x + threadIdx.x;
    if (e < E) {
        int d = ei[E + e];
        int p = rowptr[d] + atomicAdd(&fillc[d], 1);
        col[p] = ei[e];
    } else if (e < E + N) {
        int i = e - E;
        int p = rowptr[i] + atomicAdd(&fillc[i], 1);
        col[p] = i;
    }
}

// -------------------- GEMM1: h1 = x @ W1, fused per-(node,head) logits --------------------
__global__ __launch_bounds__(256) void k_gemm1(
    const float* __restrict__ x, const float* __restrict__ W,
    const float* __restrict__ attS, const float* __restrict__ attD,
    float* __restrict__ h1, float* __restrict__ as1, float* __restrict__ ad1, int N)
{
    __shared__ float Wl[128 * 128];   // 64 KB
    __shared__ float xl[8][128];
    for (int i = threadIdx.x; i < 128 * 128 / 4; i += 256)
        ((float4*)Wl)[i] = ((const float4*)W)[i];

    int lane = threadIdx.x & 31;
    int rloc = threadIdx.x >> 5;

    float aS0 = attS[lane], aS1v = attS[32 + lane], aS2 = attS[64 + lane], aS3 = attS[96 + lane];
    float aD0 = attD[lane], aD1v = attD[32 + lane], aD2 = attD[64 + lane], aD3 = attD[96 + lane];

    for (int r0 = blockIdx.x * 8; r0 < N; r0 += gridDim.x * 8) {
        __syncthreads();
        {
            int idx = threadIdx.x;           // 256 float4 = 8 rows * 32
            int rr = idx >> 5, cc = idx & 31;
            int r = r0 + rr;
            float4 v = make_float4(0.f, 0.f, 0.f, 0.f);
            if (r < N) v = ((const float4*)(x + (size_t)r * 128))[cc];
            ((float4*)&xl[rr][0])[cc] = v;
        }
        __syncthreads();
        int r = r0 + rloc;
        float acc0 = 0.f, acc1 = 0.f, acc2 = 0.f, acc3 = 0.f;
        #pragma unroll 8
        for (int k = 0; k < 128; ++k) {
            float xv = xl[rloc][k];
            const float* wr = &Wl[k * 128];
            acc0 = fmaf(xv, wr[lane], acc0);
            acc1 = fmaf(xv, wr[lane + 32], acc1);
            acc2 = fmaf(xv, wr[lane + 64], acc2);
            acc3 = fmaf(xv, wr[lane + 96], acc3);
        }
        if (r < N) {
            size_t b = (size_t)r * 128;
            h1[b + lane]      = acc0;
            h1[b + lane + 32] = acc1;
            h1[b + lane + 64] = acc2;
            h1[b + lane + 96] = acc3;
            float s0 = acc0 * aS0, s1 = acc1 * aS1v, s2 = acc2 * aS2, s3 = acc3 * aS3;
            float d0 = acc0 * aD0, d1 = acc1 * aD1v, d2 = acc2 * aD2, d3 = acc3 * aD3;
            #pragma unroll
            for (int m = 16; m >= 1; m >>= 1) {
                s0 += __shfl_xor(s0, m, 32); s1 += __shfl_xor(s1, m, 32);
                s2 += __shfl_xor(s2, m, 32); s3 += __shfl_xor(s3, m, 32);
                d0 += __shfl_xor(d0, m, 32); d1 += __shfl_xor(d1, m, 32);
                d2 += __shfl_xor(d2, m, 32); d3 += __shfl_xor(d3, m, 32);
            }
            if (lane == 0) {
                as1[r * 4 + 0] = s0; as1[r * 4 + 1] = s1; as1[r * 4 + 2] = s2; as1[r * 4 + 3] = s3;
                ad1[r * 4 + 0] = d0; ad1[r * 4 + 1] = d1; ad1[r * 4 + 2] = d2; ad1[r * 4 + 3] = d3;
            }
        }
    }
}

// -------------------- layer-1 softmax-aggregate: one wave per dst node --------------------
__global__ __launch_bounds__(256) void k_agg1(
    const float* __restrict__ h1, const float* __restrict__ as1, const float* __restrict__ ad1,
    const int* __restrict__ rowptr, const int* __restrict__ col, const float* __restrict__ b1,
    float* __restrict__ out1, int N)
{
    int wid = (int)(((unsigned)blockIdx.x * blockDim.x + threadIdx.x) >> 6);
    if (wid >= N) return;
    int lane = threadIdx.x & 63;
    int i = wid;
    int start = rowptr[i], end = rowptr[i + 1];

    float adv0 = ad1[i * 4 + 0], adv1 = ad1[i * 4 + 1];
    float adv2 = ad1[i * 4 + 2], adv3 = ad1[i * 4 + 3];

    // pass 1: softmax denominators (no max-subtraction: |alpha| <~ 4, exp is safe)
    float den0 = 0.f, den1 = 0.f, den2 = 0.f, den3 = 0.f;
    for (int e = start + lane; e < end; e += 64) {
        int src = col[e];
        const float* a = as1 + (size_t)src * 4;
        den0 += __expf(lrelu02(a[0] + adv0));
        den1 += __expf(lrelu02(a[1] + adv1));
        den2 += __expf(lrelu02(a[2] + adv2));
        den3 += __expf(lrelu02(a[3] + adv3));
    }
    #pragma unroll
    for (int m = 32; m >= 1; m >>= 1) {
        den0 += __shfl_xor(den0, m); den1 += __shfl_xor(den1, m);
        den2 += __shfl_xor(den2, m); den3 += __shfl_xor(den3, m);
    }

    int hi2 = lane >> 5;                      // lanes 0-31: heads {0,2}; 32-63: heads {1,3}
    float adA = hi2 ? adv1 : adv0;
    float adB = hi2 ? adv3 : adv2;
    float rA = 1.f / (hi2 ? den1 : den0);
    float rB = 1.f / (hi2 ? den3 : den2);

    // pass 2: weighted gather. acc0 -> channel lane (heads 0/1), acc1 -> channel 64+lane (heads 2/3)
    float acc0 = 0.f, acc1 = 0.f;
    for (int e = start; e < end; ++e) {
        int src = col[e];
        const float* a = as1 + (size_t)src * 4;
        float cA = __expf(lrelu02(a[hi2] + adA)) * rA;
        float cB = __expf(lrelu02(a[2 + hi2] + adB)) * rB;
        const float* hp = h1 + (size_t)src * 128;
        acc0 = fmaf(cA, hp[lane], acc0);
        acc1 = fmaf(cB, hp[64 + lane], acc1);
    }
    float o0 = acc0 + b1[lane];
    float o1 = acc1 + b1[64 + lane];
    o0 = o0 > 0.f ? o0 : expm1f(o0);          // ELU
    o1 = o1 > 0.f ? o1 : expm1f(o1);
    out1[(size_t)i * 128 + lane]      = o0;
    out1[(size_t)i * 128 + 64 + lane] = o1;
}

// -------------------- GEMM2: h2 = out1 @ W2, fused logits (1 head) --------------------
__global__ __launch_bounds__(256) void k_gemm2(
    const float* __restrict__ in, const float* __restrict__ W,
    const float* __restrict__ attS, const float* __restrict__ attD,
    float* __restrict__ h2, float* __restrict__ as2, float* __restrict__ ad2, int N)
{
    __shared__ float Wl[128 * 16];
    __shared__ float xl[16][132];             // pad 132: bank-conflict-free row reads
    for (int i = threadIdx.x; i < 128 * 16 / 4; i += 256)
        ((float4*)Wl)[i] = ((const float4*)W)[i];

    int c = threadIdx.x & 15;
    int rloc = threadIdx.x >> 4;
    float aSv = attS[c], aDv = attD[c];

    for (int r0 = blockIdx.x * 16; r0 < N; r0 += gridDim.x * 16) {
        __syncthreads();
        #pragma unroll
        for (int j = 0; j < 2; ++j) {
            int idx = threadIdx.x + j * 256;  // 512 float4 = 16 rows * 32
            int rr = idx >> 5, cc = idx & 31;
            int r = r0 + rr;
            float4 v = make_float4(0.f, 0.f, 0.f, 0.f);
            if (r < N) v = ((const float4*)(in + (size_t)r * 128))[cc];
            *(float4*)&xl[rr][cc * 4] = v;
        }
        __syncthreads();
        int r = r0 + rloc;
        float acc = 0.f;
        #pragma unroll 8
        for (int k = 0; k < 128; ++k)
            acc = fmaf(xl[rloc][k], Wl[k * 16 + c], acc);
        if (r < N) {
            h2[(size_t)r * 16 + c] = acc;
            float s = acc * aSv, d = acc * aDv;
            #pragma unroll
            for (int m = 8; m >= 1; m >>= 1) {
                s += __shfl_xor(s, m, 16);
                d += __shfl_xor(d, m, 16);
            }
            if (c == 0) { as2[r] = s; ad2[r] = d; }
        }
    }
}

// -------------------- layer-2 softmax-aggregate: one wave per dst node --------------------
__global__ __launch_bounds__(256) void k_agg2(
    const float* __restrict__ h2, const float* __restrict__ as2, const float* __restrict__ ad2,
    const int* __restrict__ rowptr, const int* __restrict__ col, const float* __restrict__ b2,
    float* __restrict__ out, int N)
{
    int wid = (int)(((unsigned)blockIdx.x * blockDim.x + threadIdx.x) >> 6);
    if (wid >= N) return;
    int lane = threadIdx.x & 63;
    int i = wid;
    int start = rowptr[i], end = rowptr[i + 1];
    float adv = ad2[i];

    float den = 0.f;
    for (int e = start + lane; e < end; e += 64)
        den += __expf(lrelu02(as2[col[e]] + adv));
    #pragma unroll
    for (int m = 32; m >= 1; m >>= 1) den += __shfl_xor(den, m);
    float rden = 1.f / den;

    int sub = lane >> 4, c = lane & 15;       // 4 edge-subgroups x 16 channels
    float acc = 0.f;
    for (int e = start + sub; e < end; e += 4) {
        int src = col[e];
        float coef = __expf(lrelu02(as2[src] + adv)) * rden;
        acc = fmaf(coef, h2[(size_t)src * 16 + c], acc);
    }
    acc += __shfl_xor(acc, 16);
    acc += __shfl_xor(acc, 32);
    if (lane < 16) out[(size_t)i * 16 + lane] = acc + b2[lane];
}

extern "C" void kernel_launch(void* const* d_in, const int* in_sizes, int n_in,
                              void* d_out, int out_size, void* d_ws, size_t ws_size,
                              hipStream_t stream)
{
    const float* x   = (const float*)d_in[0];
    const int*   ei  = (const int*)d_in[1];
    const float* W1  = (const float*)d_in[2];
    const float* aS1 = (const float*)d_in[3];
    const float* aD1 = (const float*)d_in[4];
    const float* b1  = (const float*)d_in[5];
    const float* W2  = (const float*)d_in[6];
    const float* aS2 = (const float*)d_in[7];
    const float* aD2 = (const float*)d_in[8];
    const float* b2  = (const float*)d_in[9];
    float* out = (float*)d_out;

    int N = in_sizes[0] / 128;
    int E = in_sizes[1] / 2;
    int ET = E + N;

    char* w = (char*)d_ws;
    auto alloc = [&](size_t bytes) -> void* {
        void* p = (void*)w;
        w += (bytes + 255) & ~(size_t)255;
        return p;
    };
    float* h1   = (float*)alloc((size_t)N * 128 * 4);
    float* out1 = (float*)alloc((size_t)N * 128 * 4);
    float* as1  = (float*)alloc((size_t)N * 4 * 4);
    float* ad1  = (float*)alloc((size_t)N * 4 * 4);
    float* h2   = (float*)alloc((size_t)N * 16 * 4);
    float* as2v = (float*)alloc((size_t)N * 4);
    float* ad2v = (float*)alloc((size_t)N * 4);
    int* deg    = (int*)alloc((size_t)N * 4);
    int* rowptr = (int*)alloc((size_t)(N + 1) * 4);
    int* fillc  = (int*)alloc((size_t)N * 4);
    int* col    = (int*)alloc((size_t)ET * 4);

    hipMemsetAsync(deg, 0, (size_t)N * 4, stream);
    hipMemsetAsync(fillc, 0, (size_t)N * 4, stream);

    const int tb = 256;
    k_deg <<<(ET + tb - 1) / tb, tb, 0, stream>>>(ei, deg, E, N);
    k_scan<<<1, 1024, 0, stream>>>(deg, rowptr, N);
    k_fill<<<(ET + tb - 1) / tb, tb, 0, stream>>>(ei, rowptr, fillc, col, E, N);

    k_gemm1<<<512, 256, 0, stream>>>(x, W1, aS1, aD1, h1, as1, ad1, N);
    k_agg1 <<<(N + 3) / 4, 256, 0, stream>>>(h1, as1, ad1, rowptr, col, b1, out1, N);
    k_gemm2<<<512, 256, 0, stream>>>(out1, W2, aS2, aD2, h2, as2v, ad2v, N);
    k_agg2 <<<(N + 3) / 4, 256, 0, stream>>>(h2, as2v, ad2v, rowptr, col, b2, out, N);
}

// Round 2
// 387.620 us; speedup vs baseline: 1.0206x; 1.0206x over previous
//
#include <hip/hip_runtime.h>

__device__ __forceinline__ float lrelu02(float a) { return a > 0.0f ? a : 0.2f * a; }

__device__ __forceinline__ unsigned bf16rne(float f) {
    unsigned u = __float_as_uint(f);
    return (u + 0x7fffu + ((u >> 16) & 1u)) >> 16;
}

// -------------------- CSR build --------------------
__global__ void k_deg(const int* __restrict__ ei, int* __restrict__ deg, int E, int N) {
    int e = blockIdx.x * blockDim.x + threadIdx.x;
    if (e < E) {
        atomicAdd(&deg[ei[E + e]], 1);
    } else if (e < E + N) {
        atomicAdd(&deg[e - E], 1);              // self loop
    }
}

__global__ __launch_bounds__(1024) void k_scan(const int* __restrict__ deg,
                                               int* __restrict__ rowptr, int N) {
    __shared__ int sums[1024];
    int t = threadIdx.x;
    int C = (N + 1023) >> 10;
    int lo = t * C;
    int hi = min(lo + C, N);
    int s = 0;
    for (int i = lo; i < hi; ++i) s += deg[i];
    sums[t] = s;
    __syncthreads();
    for (int off = 1; off < 1024; off <<= 1) {
        int v = (t >= off) ? sums[t - off] : 0;
        __syncthreads();
        sums[t] += v;
        __syncthreads();
    }
    int base = (t == 0) ? 0 : sums[t - 1];
    for (int i = lo; i < hi; ++i) { rowptr[i] = base; base += deg[i]; }
    if (t == 1023) rowptr[N] = sums[1023];
}

__global__ void k_fill(const int* __restrict__ ei, const int* __restrict__ rowptr,
                       int* __restrict__ fillc, int* __restrict__ col, int E, int N) {
    int e = blockIdx.x * blockDim.x + threadIdx.x;
    if (e < E) {
        int d = ei[E + e];
        int p = rowptr[d] + atomicAdd(&fillc[d], 1);
        col[p] = ei[e];
    } else if (e < E + N) {
        int i = e - E;
        int p = rowptr[i] + atomicAdd(&fillc[i], 1);
        col[p] = i;
    }
}

// -------------------- GEMM1: h1(bf16) = x @ W1, fused logits --------------------
// grid = 512: bid&1 = column half (64 cols), bid>>1 strides 64-row tiles.
// thread: 4 rows x 4 cols register tile -> 16 FMA per (4 b32 + 1 b128) LDS reads.
__global__ __launch_bounds__(256) void k_gemm1(
    const float* __restrict__ x, const float* __restrict__ W,
    const float* __restrict__ attS, const float* __restrict__ attD,
    unsigned short* __restrict__ h1, float* __restrict__ as1, float* __restrict__ ad1, int N)
{
    __shared__ float Wl[128 * 64];     // [k][64] for this col half: 32 KB
    __shared__ float xl[64][132];      // 64-row x tile, padded: 33.8 KB

    const int t = threadIdx.x;
    const int half = blockIdx.x & 1;
    const int cg = t & 15;             // 16 col-groups * 4 cols = 64
    const int rg = t >> 4;             // 16 row-groups * 4 rows = 64

    for (int i = t; i < 128 * 64 / 4; i += 256) {
        int k = i >> 4, c4 = (i & 15) * 4;
        *(float4*)&Wl[k * 64 + c4] = *(const float4*)&W[(size_t)k * 128 + half * 64 + c4];
    }
    float aSr[4], aDr[4];
    #pragma unroll
    for (int j = 0; j < 4; ++j) {
        aSr[j] = attS[half * 64 + cg * 4 + j];
        aDr[j] = attD[half * 64 + cg * 4 + j];
    }

    for (int r0 = (blockIdx.x >> 1) * 64; r0 < N; r0 += (gridDim.x >> 1) * 64) {
        __syncthreads();
        #pragma unroll
        for (int j = 0; j < 8; ++j) {
            int idx = t + j * 256;
            int rr = idx >> 5, cc = idx & 31;
            int r = r0 + rr;
            float4 v = make_float4(0.f, 0.f, 0.f, 0.f);
            if (r < N) v = ((const float4*)(x + (size_t)r * 128))[cc];
            *(float4*)&xl[rr][cc * 4] = v;
        }
        __syncthreads();

        float acc[4][4];
        #pragma unroll
        for (int i = 0; i < 4; ++i)
            #pragma unroll
            for (int j = 0; j < 4; ++j) acc[i][j] = 0.f;

        #pragma unroll 4
        for (int k = 0; k < 128; ++k) {
            float4 wv = *(const float4*)&Wl[k * 64 + cg * 4];
            #pragma unroll
            for (int i = 0; i < 4; ++i) {
                float xv = xl[rg * 4 + i][k];
                acc[i][0] = fmaf(xv, wv.x, acc[i][0]);
                acc[i][1] = fmaf(xv, wv.y, acc[i][1]);
                acc[i][2] = fmaf(xv, wv.z, acc[i][2]);
                acc[i][3] = fmaf(xv, wv.w, acc[i][3]);
            }
        }

        #pragma unroll
        for (int i = 0; i < 4; ++i) {
            int r = r0 + rg * 4 + i;
            float s = acc[i][0]*aSr[0] + acc[i][1]*aSr[1] + acc[i][2]*aSr[2] + acc[i][3]*aSr[3];
            float d = acc[i][0]*aDr[0] + acc[i][1]*aDr[1] + acc[i][2]*aDr[2] + acc[i][3]*aDr[3];
            s += __shfl_xor(s, 1); s += __shfl_xor(s, 2); s += __shfl_xor(s, 4);
            d += __shfl_xor(d, 1); d += __shfl_xor(d, 2); d += __shfl_xor(d, 4);
            if (r < N) {
                uint2 hv;
                hv.x = bf16rne(acc[i][0]) | (bf16rne(acc[i][1]) << 16);
                hv.y = bf16rne(acc[i][2]) | (bf16rne(acc[i][3]) << 16);
                *(uint2*)&h1[(size_t)r * 128 + half * 64 + cg * 4] = hv;
                if ((cg & 7) == 0) {
                    int head = half * 2 + (cg >> 3);
                    as1[r * 4 + head] = s;
                    ad1[r * 4 + head] = d;
                }
            }
        }
    }
}

// -------------------- layer-1 edge coefficients (one wave per dst node) --------------------
__global__ __launch_bounds__(256) void k_att1(
    const float* __restrict__ as1, const float* __restrict__ ad1,
    const int* __restrict__ rowptr, const int* __restrict__ col,
    float* __restrict__ ex1, float* __restrict__ rden1, int N)
{
    int wid = (int)(((unsigned)blockIdx.x * blockDim.x + threadIdx.x) >> 6);
    if (wid >= N) return;
    int lane = threadIdx.x & 63;
    int start = rowptr[wid], end = rowptr[wid + 1];
    const float4 ad = *(const float4*)(ad1 + (size_t)wid * 4);

    float den0 = 0.f, den1 = 0.f, den2 = 0.f, den3 = 0.f;
    for (int e = start + lane; e < end; e += 64) {
        int src = col[e];
        const float4 a = *(const float4*)(as1 + (size_t)src * 4);
        float e0 = __expf(lrelu02(a.x + ad.x));
        float e1 = __expf(lrelu02(a.y + ad.y));
        float e2 = __expf(lrelu02(a.z + ad.z));
        float e3 = __expf(lrelu02(a.w + ad.w));
        *(float4*)(ex1 + (size_t)e * 4) = make_float4(e0, e1, e2, e3);
        den0 += e0; den1 += e1; den2 += e2; den3 += e3;
    }
    #pragma unroll
    for (int m = 32; m >= 1; m >>= 1) {
        den0 += __shfl_xor(den0, m); den1 += __shfl_xor(den1, m);
        den2 += __shfl_xor(den2, m); den3 += __shfl_xor(den3, m);
    }
    if (lane == 0)
        *(float4*)(rden1 + (size_t)wid * 4) =
            make_float4(1.f / den0, 1.f / den1, 1.f / den2, 1.f / den3);
}

// -------------------- layer-1 aggregate: one wave per dst node --------------------
__global__ __launch_bounds__(256) void k_agg1(
    const unsigned short* __restrict__ h1, const float* __restrict__ ex1,
    const float* __restrict__ rden1, const int* __restrict__ rowptr,
    const int* __restrict__ col, const float* __restrict__ b1,
    float* __restrict__ out1, int N)
{
    int wid = (int)(((unsigned)blockIdx.x * blockDim.x + threadIdx.x) >> 6);
    if (wid >= N) return;
    int lane = threadIdx.x & 63;
    int head = lane >> 4;                       // channels {2*lane, 2*lane+1}, head = lane/16
    float rden = rden1[wid * 4 + head];
    int start = rowptr[wid], end = rowptr[wid + 1];

    float acc0 = 0.f, acc1 = 0.f;
    for (int e = start; e < end; ++e) {
        int src = col[e];
        float4 ev = *(const float4*)(ex1 + (size_t)e * 4);
        float exv = head < 2 ? (head == 0 ? ev.x : ev.y) : (head == 2 ? ev.z : ev.w);
        float coef = exv * rden;
        unsigned hv = *(const unsigned*)(h1 + (size_t)src * 128 + lane * 2);
        float lo = __uint_as_float(hv << 16);
        float hi = __uint_as_float(hv & 0xffff0000u);
        acc0 = fmaf(coef, lo, acc0);
        acc1 = fmaf(coef, hi, acc1);
    }
    int c0 = lane * 2;
    float o0 = acc0 + b1[c0];
    float o1 = acc1 + b1[c0 + 1];
    o0 = o0 > 0.f ? o0 : expm1f(o0);
    o1 = o1 > 0.f ? o1 : expm1f(o1);
    *(float2*)&out1[(size_t)wid * 128 + c0] = make_float2(o0, o1);
}

// -------------------- GEMM2: h2 = out1 @ W2, fused logits --------------------
__global__ __launch_bounds__(256) void k_gemm2(
    const float* __restrict__ in, const float* __restrict__ W,
    const float* __restrict__ attS, const float* __restrict__ attD,
    float* __restrict__ h2, float* __restrict__ as2, float* __restrict__ ad2, int N)
{
    __shared__ float Wl[128 * 16];
    __shared__ float xl[64][132];
    const int t = threadIdx.x;
    const int cg = t & 3;                 // 4 col-groups * 4 cols = 16
    const int rloc = t >> 2;              // 64 rows

    for (int i = t; i < 128 * 16 / 4; i += 256)
        ((float4*)Wl)[i] = ((const float4*)W)[i];
    float aSr[4], aDr[4];
    #pragma unroll
    for (int j = 0; j < 4; ++j) { aSr[j] = attS[cg * 4 + j]; aDr[j] = attD[cg * 4 + j]; }

    for (int r0 = blockIdx.x * 64; r0 < N; r0 += gridDim.x * 64) {
        __syncthreads();
        #pragma unroll
        for (int j = 0; j < 8; ++j) {
            int idx = t + j * 256;
            int rr = idx >> 5, cc = idx & 31;
            int r = r0 + rr;
            float4 v = make_float4(0.f, 0.f, 0.f, 0.f);
            if (r < N) v = ((const float4*)(in + (size_t)r * 128))[cc];
            *(float4*)&xl[rr][cc * 4] = v;
        }
        __syncthreads();

        float acc[4] = {0.f, 0.f, 0.f, 0.f};
        #pragma unroll 4
        for (int k = 0; k < 128; ++k) {
            float xv = xl[rloc][k];
            float4 wv = *(const float4*)&Wl[k * 16 + cg * 4];
            acc[0] = fmaf(xv, wv.x, acc[0]);
            acc[1] = fmaf(xv, wv.y, acc[1]);
            acc[2] = fmaf(xv, wv.z, acc[2]);
            acc[3] = fmaf(xv, wv.w, acc[3]);
        }
        int r = r0 + rloc;
        float s = acc[0]*aSr[0] + acc[1]*aSr[1] + acc[2]*aSr[2] + acc[3]*aSr[3];
        float d = acc[0]*aDr[0] + acc[1]*aDr[1] + acc[2]*aDr[2] + acc[3]*aDr[3];
        s += __shfl_xor(s, 1); s += __shfl_xor(s, 2);
        d += __shfl_xor(d, 1); d += __shfl_xor(d, 2);
        if (r < N) {
            *(float4*)&h2[(size_t)r * 16 + cg * 4] = make_float4(acc[0], acc[1], acc[2], acc[3]);
            if (cg == 0) { as2[r] = s; ad2[r] = d; }
        }
    }
}

// -------------------- layer-2 edge coefficients --------------------
__global__ __launch_bounds__(256) void k_att2(
    const float* __restrict__ as2, const float* __restrict__ ad2,
    const int* __restrict__ rowptr, const int* __restrict__ col,
    float* __restrict__ ex2, float* __restrict__ rden2, int N)
{
    int wid = (int)(((unsigned)blockIdx.x * blockDim.x + threadIdx.x) >> 6);
    if (wid >= N) return;
    int lane = threadIdx.x & 63;
    int start = rowptr[wid], end = rowptr[wid + 1];
    float adv = ad2[wid];
    float den = 0.f;
    for (int e = start + lane; e < end; e += 64) {
        float ev = __expf(lrelu02(as2[col[e]] + adv));
        ex2[e] = ev;
        den += ev;
    }
    #pragma unroll
    for (int m = 32; m >= 1; m >>= 1) den += __shfl_xor(den, m);
    if (lane == 0) rden2[wid] = 1.f / den;
}

// -------------------- layer-2 aggregate --------------------
__global__ __launch_bounds__(256) void k_agg2(
    const float* __restrict__ h2, const float* __restrict__ ex2,
    const float* __restrict__ rden2, const int* __restrict__ rowptr,
    const int* __restrict__ col, const float* __restrict__ b2,
    float* __restrict__ out, int N)
{
    int wid = (int)(((unsigned)blockIdx.x * blockDim.x + threadIdx.x) >> 6);
    if (wid >= N) return;
    int lane = threadIdx.x & 63;
    int start = rowptr[wid], end = rowptr[wid + 1];
    float rden = rden2[wid];
    int sub = lane >> 4, c = lane & 15;
    float acc = 0.f;
    for (int e = start + sub; e < end; e += 4) {
        int src = col[e];
        float coef = ex2[e] * rden;
        acc = fmaf(coef, h2[(size_t)src * 16 + c], acc);
    }
    acc += __shfl_xor(acc, 16);
    acc += __shfl_xor(acc, 32);
    if (lane < 16) out[(size_t)wid * 16 + lane] = acc + b2[lane];
}

extern "C" void kernel_launch(void* const* d_in, const int* in_sizes, int n_in,
                              void* d_out, int out_size, void* d_ws, size_t ws_size,
                              hipStream_t stream)
{
    const float* x   = (const float*)d_in[0];
    const int*   ei  = (const int*)d_in[1];
    const float* W1  = (const float*)d_in[2];
    const float* aS1 = (const float*)d_in[3];
    const float* aD1 = (const float*)d_in[4];
    const float* b1  = (const float*)d_in[5];
    const float* W2  = (const float*)d_in[6];
    const float* aS2 = (const float*)d_in[7];
    const float* aD2 = (const float*)d_in[8];
    const float* b2  = (const float*)d_in[9];
    float* out = (float*)d_out;

    int N = in_sizes[0] / 128;
    int E = in_sizes[1] / 2;
    int ET = E + N;

    char* w = (char*)d_ws;
    auto alloc = [&](size_t bytes) -> void* {
        void* p = (void*)w;
        w += (bytes + 255) & ~(size_t)255;
        return p;
    };
    unsigned short* h1 = (unsigned short*)alloc((size_t)N * 128 * 2);   // bf16
    float* out1  = (float*)alloc((size_t)N * 128 * 4);
    float* as1   = (float*)alloc((size_t)N * 4 * 4);
    float* ad1   = (float*)alloc((size_t)N * 4 * 4);
    float* rden1 = (float*)alloc((size_t)N * 4 * 4);
    float* h2    = (float*)alloc((size_t)N * 16 * 4);
    float* as2v  = (float*)alloc((size_t)N * 4);
    float* ad2v  = (float*)alloc((size_t)N * 4);
    float* rden2 = (float*)alloc((size_t)N * 4);
    float* ex1   = (float*)alloc((size_t)ET * 4 * 4);
    float* ex2   = (float*)alloc((size_t)ET * 4);
    int* deg     = (int*)alloc((size_t)N * 4);
    int* rowptr  = (int*)alloc((size_t)(N + 1) * 4);
    int* fillc   = (int*)alloc((size_t)N * 4);
    int* col     = (int*)alloc((size_t)ET * 4);

    hipMemsetAsync(deg, 0, (size_t)N * 4, stream);
    hipMemsetAsync(fillc, 0, (size_t)N * 4, stream);

    const int tb = 256;
    k_deg <<<(ET + tb - 1) / tb, tb, 0, stream>>>(ei, deg, E, N);
    k_scan<<<1, 1024, 0, stream>>>(deg, rowptr, N);
    k_fill<<<(ET + tb - 1) / tb, tb, 0, stream>>>(ei, rowptr, fillc, col, E, N);

    k_gemm1<<<512, 256, 0, stream>>>(x, W1, aS1, aD1, h1, as1, ad1, N);
    k_att1 <<<(N + 3) / 4, tb, 0, stream>>>(as1, ad1, rowptr, col, ex1, rden1, N);
    k_agg1 <<<(N + 3) / 4, tb, 0, stream>>>(h1, ex1, rden1, rowptr, col, b1, out1, N);
    k_gemm2<<<512, 256, 0, stream>>>(out1, W2, aS2, aD2, h2, as2v, ad2v, N);
    k_att2 <<<(N + 3) / 4, tb, 0, stream>>>(as2v, ad2v, rowptr, col, ex2, rden2, N);
    k_agg2 <<<(N + 3) / 4, tb, 0, stream>>>(h2, ex2, rden2, rowptr, col, b2, out, N);
}

// Round 3
// 294.393 us; speedup vs baseline: 1.3438x; 1.3167x over previous
//
#include <hip/hip_runtime.h>

__device__ __forceinline__ float lrelu02(float a) { return a > 0.0f ? a : 0.2f * a; }

__device__ __forceinline__ unsigned bf16rne(float f) {
    unsigned u = __float_as_uint(f);
    return (u + 0x7fffu + ((u >> 16) & 1u)) >> 16;
}

// -------------------- CSR build --------------------
__global__ void k_deg(const int* __restrict__ ei, int* __restrict__ deg, int E, int N) {
    int e = blockIdx.x * blockDim.x + threadIdx.x;
    if (e < E) {
        atomicAdd(&deg[ei[E + e]], 1);
    } else if (e < E + N) {
        atomicAdd(&deg[e - E], 1);              // self loop
    }
}

__global__ __launch_bounds__(1024) void k_scan(const int* __restrict__ deg,
                                               int* __restrict__ rowptr, int N) {
    __shared__ int sums[1024];
    int t = threadIdx.x;
    int C = (N + 1023) >> 10;
    int lo = t * C;
    int hi = min(lo + C, N);
    int s = 0;
    for (int i = lo; i < hi; ++i) s += deg[i];
    sums[t] = s;
    __syncthreads();
    for (int off = 1; off < 1024; off <<= 1) {
        int v = (t >= off) ? sums[t - off] : 0;
        __syncthreads();
        sums[t] += v;
        __syncthreads();
    }
    int base = (t == 0) ? 0 : sums[t - 1];
    for (int i = lo; i < hi; ++i) { rowptr[i] = base; base += deg[i]; }
    if (t == 1023) rowptr[N] = sums[1023];
}

__global__ void k_fill(const int* __restrict__ ei, const int* __restrict__ rowptr,
                       int* __restrict__ fillc, int* __restrict__ col, int E, int N) {
    int e = blockIdx.x * blockDim.x + threadIdx.x;
    if (e < E) {
        int d = ei[E + e];
        int p = rowptr[d] + atomicAdd(&fillc[d], 1);
        col[p] = ei[e];
    } else if (e < E + N) {
        int i = e - E;
        int p = rowptr[i] + atomicAdd(&fillc[i], 1);
        col[p] = i;
    }
}

// -------------------- GEMM1: h1(bf16) = x @ W1, fused logits --------------------
__global__ __launch_bounds__(256) void k_gemm1(
    const float* __restrict__ x, const float* __restrict__ W,
    const float* __restrict__ attS, const float* __restrict__ attD,
    unsigned short* __restrict__ h1, float* __restrict__ as1, float* __restrict__ ad1, int N)
{
    __shared__ float Wl[128 * 64];     // [k][64] for this col half: 32 KB
    __shared__ float xl[64][132];      // 64-row x tile, padded: 33.8 KB

    const int t = threadIdx.x;
    const int half = blockIdx.x & 1;
    const int cg = t & 15;             // 16 col-groups * 4 cols = 64
    const int rg = t >> 4;             // 16 row-groups * 4 rows = 64

    for (int i = t; i < 128 * 64 / 4; i += 256) {
        int k = i >> 4, c4 = (i & 15) * 4;
        *(float4*)&Wl[k * 64 + c4] = *(const float4*)&W[(size_t)k * 128 + half * 64 + c4];
    }
    float aSr[4], aDr[4];
    #pragma unroll
    for (int j = 0; j < 4; ++j) {
        aSr[j] = attS[half * 64 + cg * 4 + j];
        aDr[j] = attD[half * 64 + cg * 4 + j];
    }

    for (int r0 = (blockIdx.x >> 1) * 64; r0 < N; r0 += (gridDim.x >> 1) * 64) {
        __syncthreads();
        #pragma unroll
        for (int j = 0; j < 8; ++j) {
            int idx = t + j * 256;
            int rr = idx >> 5, cc = idx & 31;
            int r = r0 + rr;
            float4 v = make_float4(0.f, 0.f, 0.f, 0.f);
            if (r < N) v = ((const float4*)(x + (size_t)r * 128))[cc];
            *(float4*)&xl[rr][cc * 4] = v;
        }
        __syncthreads();

        float acc[4][4];
        #pragma unroll
        for (int i = 0; i < 4; ++i)
            #pragma unroll
            for (int j = 0; j < 4; ++j) acc[i][j] = 0.f;

        #pragma unroll 4
        for (int k = 0; k < 128; ++k) {
            float4 wv = *(const float4*)&Wl[k * 64 + cg * 4];
            #pragma unroll
            for (int i = 0; i < 4; ++i) {
                float xv = xl[rg * 4 + i][k];
                acc[i][0] = fmaf(xv, wv.x, acc[i][0]);
                acc[i][1] = fmaf(xv, wv.y, acc[i][1]);
                acc[i][2] = fmaf(xv, wv.z, acc[i][2]);
                acc[i][3] = fmaf(xv, wv.w, acc[i][3]);
            }
        }

        #pragma unroll
        for (int i = 0; i < 4; ++i) {
            int r = r0 + rg * 4 + i;
            float s = acc[i][0]*aSr[0] + acc[i][1]*aSr[1] + acc[i][2]*aSr[2] + acc[i][3]*aSr[3];
            float d = acc[i][0]*aDr[0] + acc[i][1]*aDr[1] + acc[i][2]*aDr[2] + acc[i][3]*aDr[3];
            s += __shfl_xor(s, 1); s += __shfl_xor(s, 2); s += __shfl_xor(s, 4);
            d += __shfl_xor(d, 1); d += __shfl_xor(d, 2); d += __shfl_xor(d, 4);
            if (r < N) {
                uint2 hv;
                hv.x = bf16rne(acc[i][0]) | (bf16rne(acc[i][1]) << 16);
                hv.y = bf16rne(acc[i][2]) | (bf16rne(acc[i][3]) << 16);
                *(uint2*)&h1[(size_t)r * 128 + half * 64 + cg * 4] = hv;
                if ((cg & 7) == 0) {
                    int head = half * 2 + (cg >> 3);
                    as1[r * 4 + head] = s;
                    ad1[r * 4 + head] = d;
                }
            }
        }
    }
}

// -------------------- layer-1 edge coefficients (one wave per dst node) --------------------
__global__ __launch_bounds__(256) void k_att1(
    const float* __restrict__ as1, const float* __restrict__ ad1,
    const int* __restrict__ rowptr, const int* __restrict__ col,
    float* __restrict__ ex1, float* __restrict__ rden1, int N)
{
    int wid = (int)(((unsigned)blockIdx.x * blockDim.x + threadIdx.x) >> 6);
    if (wid >= N) return;
    int lane = threadIdx.x & 63;
    int start = rowptr[wid], end = rowptr[wid + 1];
    const float4 ad = *(const float4*)(ad1 + (size_t)wid * 4);

    float den0 = 0.f, den1 = 0.f, den2 = 0.f, den3 = 0.f;
    for (int e = start + lane; e < end; e += 64) {
        int src = col[e];
        const float4 a = *(const float4*)(as1 + (size_t)src * 4);
        float e0 = __expf(lrelu02(a.x + ad.x));
        float e1 = __expf(lrelu02(a.y + ad.y));
        float e2 = __expf(lrelu02(a.z + ad.z));
        float e3 = __expf(lrelu02(a.w + ad.w));
        *(float4*)(ex1 + (size_t)e * 4) = make_float4(e0, e1, e2, e3);
        den0 += e0; den1 += e1; den2 += e2; den3 += e3;
    }
    #pragma unroll
    for (int m = 32; m >= 1; m >>= 1) {
        den0 += __shfl_xor(den0, m); den1 += __shfl_xor(den1, m);
        den2 += __shfl_xor(den2, m); den3 += __shfl_xor(den3, m);
    }
    if (lane == 0)
        *(float4*)(rden1 + (size_t)wid * 4) =
            make_float4(1.f / den0, 1.f / den1, 1.f / den2, 1.f / den3);
}

// -------------------- layer-1 aggregate: one wave per dst node, 8 gathers in flight ------
__global__ __launch_bounds__(256) void k_agg1(
    const unsigned short* __restrict__ h1, const float* __restrict__ ex1,
    const float* __restrict__ rden1, const int* __restrict__ rowptr,
    const int* __restrict__ col, const float* __restrict__ b1,
    float* __restrict__ out1, int N)
{
    int wid = (int)(((unsigned)blockIdx.x * blockDim.x + threadIdx.x) >> 6);
    if (wid >= N) return;
    int lane = threadIdx.x & 63;
    int head = lane >> 4;                       // channels {2*lane, 2*lane+1}
    float rden = rden1[wid * 4 + head];
    int start = rowptr[wid], end = rowptr[wid + 1];

    float acc0 = 0.f, acc1 = 0.f;
    for (int e = start; e < end; e += 8) {
        int   s[8];
        float cf[8];
        unsigned hv[8];
        #pragma unroll
        for (int j = 0; j < 8; ++j) {
            int ee = e + j;
            bool ok = ee < end;
            int es = ok ? ee : e;               // clamp to a valid edge
            s[j]  = col[es];
            cf[j] = ok ? ex1[(size_t)es * 4 + head] : 0.f;
        }
        #pragma unroll
        for (int j = 0; j < 8; ++j)
            hv[j] = *(const unsigned*)(h1 + (size_t)s[j] * 128 + lane * 2);
        #pragma unroll
        for (int j = 0; j < 8; ++j) {
            float coef = cf[j] * rden;
            acc0 = fmaf(coef, __uint_as_float(hv[j] << 16), acc0);
            acc1 = fmaf(coef, __uint_as_float(hv[j] & 0xffff0000u), acc1);
        }
    }
    int c0 = lane * 2;
    float o0 = acc0 + b1[c0];
    float o1 = acc1 + b1[c0 + 1];
    o0 = o0 > 0.f ? o0 : expm1f(o0);
    o1 = o1 > 0.f ? o1 : expm1f(o1);
    *(float2*)&out1[(size_t)wid * 128 + c0] = make_float2(o0, o1);
}

// -------------------- GEMM2: h2 = out1 @ W2, fused logits --------------------
__global__ __launch_bounds__(256) void k_gemm2(
    const float* __restrict__ in, const float* __restrict__ W,
    const float* __restrict__ attS, const float* __restrict__ attD,
    float* __restrict__ h2, float* __restrict__ as2, float* __restrict__ ad2, int N)
{
    __shared__ float Wl[128 * 16];
    __shared__ float xl[64][132];
    const int t = threadIdx.x;
    const int cg = t & 3;                 // 4 col-groups * 4 cols = 16
    const int rloc = t >> 2;              // 64 rows

    for (int i = t; i < 128 * 16 / 4; i += 256)
        ((float4*)Wl)[i] = ((const float4*)W)[i];
    float aSr[4], aDr[4];
    #pragma unroll
    for (int j = 0; j < 4; ++j) { aSr[j] = attS[cg * 4 + j]; aDr[j] = attD[cg * 4 + j]; }

    for (int r0 = blockIdx.x * 64; r0 < N; r0 += gridDim.x * 64) {
        __syncthreads();
        #pragma unroll
        for (int j = 0; j < 8; ++j) {
            int idx = t + j * 256;
            int rr = idx >> 5, cc = idx & 31;
            int r = r0 + rr;
            float4 v = make_float4(0.f, 0.f, 0.f, 0.f);
            if (r < N) v = ((const float4*)(in + (size_t)r * 128))[cc];
            *(float4*)&xl[rr][cc * 4] = v;
        }
        __syncthreads();

        float acc[4] = {0.f, 0.f, 0.f, 0.f};
        #pragma unroll 4
        for (int k = 0; k < 128; ++k) {
            float xv = xl[rloc][k];
            float4 wv = *(const float4*)&Wl[k * 16 + cg * 4];
            acc[0] = fmaf(xv, wv.x, acc[0]);
            acc[1] = fmaf(xv, wv.y, acc[1]);
            acc[2] = fmaf(xv, wv.z, acc[2]);
            acc[3] = fmaf(xv, wv.w, acc[3]);
        }
        int r = r0 + rloc;
        float s = acc[0]*aSr[0] + acc[1]*aSr[1] + acc[2]*aSr[2] + acc[3]*aSr[3];
        float d = acc[0]*aDr[0] + acc[1]*aDr[1] + acc[2]*aDr[2] + acc[3]*aDr[3];
        s += __shfl_xor(s, 1); s += __shfl_xor(s, 2);
        d += __shfl_xor(d, 1); d += __shfl_xor(d, 2);
        if (r < N) {
            *(float4*)&h2[(size_t)r * 16 + cg * 4] = make_float4(acc[0], acc[1], acc[2], acc[3]);
            if (cg == 0) { as2[r] = s; ad2[r] = d; }
        }
    }
}

// -------------------- layer-2 edge coefficients --------------------
__global__ __launch_bounds__(256) void k_att2(
    const float* __restrict__ as2, const float* __restrict__ ad2,
    const int* __restrict__ rowptr, const int* __restrict__ col,
    float* __restrict__ ex2, float* __restrict__ rden2, int N)
{
    int wid = (int)(((unsigned)blockIdx.x * blockDim.x + threadIdx.x) >> 6);
    if (wid >= N) return;
    int lane = threadIdx.x & 63;
    int start = rowptr[wid], end = rowptr[wid + 1];
    float adv = ad2[wid];
    float den = 0.f;
    for (int e = start + lane; e < end; e += 64) {
        float ev = __expf(lrelu02(as2[col[e]] + adv));
        ex2[e] = ev;
        den += ev;
    }
    #pragma unroll
    for (int m = 32; m >= 1; m >>= 1) den += __shfl_xor(den, m);
    if (lane == 0) rden2[wid] = 1.f / den;
}

// -------------------- layer-2 aggregate: 4 subgroups x unroll 4 = 16 gathers in flight ---
__global__ __launch_bounds__(256) void k_agg2(
    const float* __restrict__ h2, const float* __restrict__ ex2,
    const float* __restrict__ rden2, const int* __restrict__ rowptr,
    const int* __restrict__ col, const float* __restrict__ b2,
    float* __restrict__ out, int N)
{
    int wid = (int)(((unsigned)blockIdx.x * blockDim.x + threadIdx.x) >> 6);
    if (wid >= N) return;
    int lane = threadIdx.x & 63;
    int start = rowptr[wid], end = rowptr[wid + 1];
    float rden = rden2[wid];
    int sub = lane >> 4, c = lane & 15;
    float acc = 0.f;
    for (int e0 = start + sub; e0 < end; e0 += 16) {
        int   s[4];
        float cf[4];
        float hvv[4];
        #pragma unroll
        for (int j = 0; j < 4; ++j) {
            int ee = e0 + j * 4;
            bool ok = ee < end;
            int es = ok ? ee : e0;
            s[j]  = col[es];
            cf[j] = ok ? ex2[es] : 0.f;
        }
        #pragma unroll
        for (int j = 0; j < 4; ++j)
            hvv[j] = h2[(size_t)s[j] * 16 + c];
        #pragma unroll
        for (int j = 0; j < 4; ++j)
            acc = fmaf(cf[j] * rden, hvv[j], acc);
    }
    acc += __shfl_xor(acc, 16);
    acc += __shfl_xor(acc, 32);
    if (lane < 16) out[(size_t)wid * 16 + lane] = acc + b2[lane];
}

extern "C" void kernel_launch(void* const* d_in, const int* in_sizes, int n_in,
                              void* d_out, int out_size, void* d_ws, size_t ws_size,
                              hipStream_t stream)
{
    const float* x   = (const float*)d_in[0];
    const int*   ei  = (const int*)d_in[1];
    const float* W1  = (const float*)d_in[2];
    const float* aS1 = (const float*)d_in[3];
    const float* aD1 = (const float*)d_in[4];
    const float* b1  = (const float*)d_in[5];
    const float* W2  = (const float*)d_in[6];
    const float* aS2 = (const float*)d_in[7];
    const float* aD2 = (const float*)d_in[8];
    const float* b2  = (const float*)d_in[9];
    float* out = (float*)d_out;

    int N = in_sizes[0] / 128;
    int E = in_sizes[1] / 2;
    int ET = E + N;

    char* w = (char*)d_ws;
    auto alloc = [&](size_t bytes) -> void* {
        void* p = (void*)w;
        w += (bytes + 255) & ~(size_t)255;
        return p;
    };
    unsigned short* h1 = (unsigned short*)alloc((size_t)N * 128 * 2);   // bf16
    float* out1  = (float*)alloc((size_t)N * 128 * 4);
    float* as1   = (float*)alloc((size_t)N * 4 * 4);
    float* ad1   = (float*)alloc((size_t)N * 4 * 4);
    float* rden1 = (float*)alloc((size_t)N * 4 * 4);
    float* h2    = (float*)alloc((size_t)N * 16 * 4);
    float* as2v  = (float*)alloc((size_t)N * 4);
    float* ad2v  = (float*)alloc((size_t)N * 4);
    float* rden2 = (float*)alloc((size_t)N * 4);
    float* ex1   = (float*)alloc((size_t)ET * 4 * 4);
    float* ex2   = (float*)alloc((size_t)ET * 4);
    int* deg     = (int*)alloc((size_t)N * 4);
    int* rowptr  = (int*)alloc((size_t)(N + 1) * 4);
    int* fillc   = (int*)alloc((size_t)N * 4);
    int* col     = (int*)alloc((size_t)ET * 4);

    hipMemsetAsync(deg, 0, (size_t)N * 4, stream);
    hipMemsetAsync(fillc, 0, (size_t)N * 4, stream);

    const int tb = 256;
    k_deg <<<(ET + tb - 1) / tb, tb, 0, stream>>>(ei, deg, E, N);
    k_scan<<<1, 1024, 0, stream>>>(deg, rowptr, N);
    k_fill<<<(ET + tb - 1) / tb, tb, 0, stream>>>(ei, rowptr, fillc, col, E, N);

    k_gemm1<<<512, 256, 0, stream>>>(x, W1, aS1, aD1, h1, as1, ad1, N);
    k_att1 <<<(N + 3) / 4, tb, 0, stream>>>(as1, ad1, rowptr, col, ex1, rden1, N);
    k_agg1 <<<(N + 3) / 4, tb, 0, stream>>>(h1, ex1, rden1, rowptr, col, b1, out1, N);
    k_gemm2<<<512, 256, 0, stream>>>(out1, W2, aS2, aD2, h2, as2v, ad2v, N);
    k_att2 <<<(N + 3) / 4, tb, 0, stream>>>(as2v, ad2v, rowptr, col, ex2, rden2, N);
    k_agg2 <<<(N + 3) / 4, tb, 0, stream>>>(h2, ex2, rden2, rowptr, col, b2, out, N);
}

// Round 4
// 233.659 us; speedup vs baseline: 1.6930x; 1.2599x over previous
//
#include <hip/hip_runtime.h>

__device__ __forceinline__ float lrelu02(float a) { return a > 0.0f ? a : 0.2f * a; }

__device__ __forceinline__ unsigned bf16rne(float f) {
    unsigned u = __float_as_uint(f);
    return (u + 0x7fffu + ((u >> 16) & 1u)) >> 16;
}

// -------------------- CSR build --------------------
__global__ void k_deg(const int* __restrict__ ei, int* __restrict__ deg, int E, int N) {
    int e = blockIdx.x * blockDim.x + threadIdx.x;
    if (e < E) {
        atomicAdd(&deg[ei[E + e]], 1);
    } else if (e < E + N) {
        atomicAdd(&deg[e - E], 1);              // self loop
    }
}

// 3-phase hierarchical exclusive scan over deg[N] -> rowptr[N+1]
// phase 1: 2048 elems/block (256 thr x 8), local scan + block sum
__global__ __launch_bounds__(256) void k_scan_local(
    const int* __restrict__ deg, int* __restrict__ rowptr, int* __restrict__ bsum, int N)
{
    const int t = threadIdx.x;
    const int base = blockIdx.x * 2048 + t * 8;
    int v[8];
    int s = 0;
    #pragma unroll
    for (int j = 0; j < 8; ++j) {
        int idx = base + j;
        v[j] = (idx < N) ? deg[idx] : 0;
        s += v[j];
    }
    __shared__ int ts[256];
    ts[t] = s;
    __syncthreads();
    #pragma unroll
    for (int off = 1; off < 256; off <<= 1) {
        int u = (t >= off) ? ts[t - off] : 0;
        __syncthreads();
        ts[t] += u;
        __syncthreads();
    }
    int ex = (t == 0) ? 0 : ts[t - 1];
    #pragma unroll
    for (int j = 0; j < 8; ++j) {
        int idx = base + j;
        if (idx < N) rowptr[idx] = ex;
        ex += v[j];
    }
    if (t == 255) bsum[blockIdx.x] = ts[255];
}

// phase 2: one wave exclusive-scans the block sums (nblk <= 64)
__global__ void k_scan_bsum(int* __restrict__ bsum, int nblk) {
    int t = threadIdx.x;
    int v = (t < nblk) ? bsum[t] : 0;
    int inc = v;
    #pragma unroll
    for (int off = 1; off < 64; off <<= 1) {
        int u = __shfl_up(inc, off);
        if (t >= off) inc += u;
    }
    if (t < nblk) bsum[t] = inc - v;
}

// phase 3: add block offsets in place; write rowptr[N]
__global__ __launch_bounds__(256) void k_scan_add(
    int* __restrict__ rowptr, const int* __restrict__ bsum, int N, int ET)
{
    const int t = threadIdx.x;
    const int base = blockIdx.x * 2048 + t * 8;
    int off = bsum[blockIdx.x];
    #pragma unroll
    for (int j = 0; j < 8; ++j) {
        int idx = base + j;
        if (idx < N) rowptr[idx] += off;
    }
    if (blockIdx.x == 0 && t == 0) rowptr[N] = ET;
}

__global__ void k_fill(const int* __restrict__ ei, const int* __restrict__ rowptr,
                       int* __restrict__ fillc, int* __restrict__ col, int E, int N) {
    int e = blockIdx.x * blockDim.x + threadIdx.x;
    if (e < E) {
        int d = ei[E + e];
        int p = rowptr[d] + atomicAdd(&fillc[d], 1);
        col[p] = ei[e];
    } else if (e < E + N) {
        int i = e - E;
        int p = rowptr[i] + atomicAdd(&fillc[i], 1);
        col[p] = i;
    }
}

// -------------------- GEMM1: h1(bf16) = x @ W1, fused logits --------------------
__global__ __launch_bounds__(256) void k_gemm1(
    const float* __restrict__ x, const float* __restrict__ W,
    const float* __restrict__ attS, const float* __restrict__ attD,
    unsigned short* __restrict__ h1, float* __restrict__ as1, float* __restrict__ ad1, int N)
{
    __shared__ float Wl[128 * 64];     // [k][64] for this col half: 32 KB
    __shared__ float xl[64][132];      // 64-row x tile, padded: 33.8 KB

    const int t = threadIdx.x;
    const int half = blockIdx.x & 1;
    const int cg = t & 15;             // 16 col-groups * 4 cols = 64
    const int rg = t >> 4;             // 16 row-groups * 4 rows = 64

    for (int i = t; i < 128 * 64 / 4; i += 256) {
        int k = i >> 4, c4 = (i & 15) * 4;
        *(float4*)&Wl[k * 64 + c4] = *(const float4*)&W[(size_t)k * 128 + half * 64 + c4];
    }
    float aSr[4], aDr[4];
    #pragma unroll
    for (int j = 0; j < 4; ++j) {
        aSr[j] = attS[half * 64 + cg * 4 + j];
        aDr[j] = attD[half * 64 + cg * 4 + j];
    }

    for (int r0 = (blockIdx.x >> 1) * 64; r0 < N; r0 += (gridDim.x >> 1) * 64) {
        __syncthreads();
        #pragma unroll
        for (int j = 0; j < 8; ++j) {
            int idx = t + j * 256;
            int rr = idx >> 5, cc = idx & 31;
            int r = r0 + rr;
            float4 v = make_float4(0.f, 0.f, 0.f, 0.f);
            if (r < N) v = ((const float4*)(x + (size_t)r * 128))[cc];
            *(float4*)&xl[rr][cc * 4] = v;
        }
        __syncthreads();

        float acc[4][4];
        #pragma unroll
        for (int i = 0; i < 4; ++i)
            #pragma unroll
            for (int j = 0; j < 4; ++j) acc[i][j] = 0.f;

        #pragma unroll 4
        for (int k = 0; k < 128; ++k) {
            float4 wv = *(const float4*)&Wl[k * 64 + cg * 4];
            #pragma unroll
            for (int i = 0; i < 4; ++i) {
                float xv = xl[rg * 4 + i][k];
                acc[i][0] = fmaf(xv, wv.x, acc[i][0]);
                acc[i][1] = fmaf(xv, wv.y, acc[i][1]);
                acc[i][2] = fmaf(xv, wv.z, acc[i][2]);
                acc[i][3] = fmaf(xv, wv.w, acc[i][3]);
            }
        }

        #pragma unroll
        for (int i = 0; i < 4; ++i) {
            int r = r0 + rg * 4 + i;
            float s = acc[i][0]*aSr[0] + acc[i][1]*aSr[1] + acc[i][2]*aSr[2] + acc[i][3]*aSr[3];
            float d = acc[i][0]*aDr[0] + acc[i][1]*aDr[1] + acc[i][2]*aDr[2] + acc[i][3]*aDr[3];
            s += __shfl_xor(s, 1); s += __shfl_xor(s, 2); s += __shfl_xor(s, 4);
            d += __shfl_xor(d, 1); d += __shfl_xor(d, 2); d += __shfl_xor(d, 4);
            if (r < N) {
                uint2 hv;
                hv.x = bf16rne(acc[i][0]) | (bf16rne(acc[i][1]) << 16);
                hv.y = bf16rne(acc[i][2]) | (bf16rne(acc[i][3]) << 16);
                *(uint2*)&h1[(size_t)r * 128 + half * 64 + cg * 4] = hv;
                if ((cg & 7) == 0) {
                    int head = half * 2 + (cg >> 3);
                    as1[r * 4 + head] = s;
                    ad1[r * 4 + head] = d;
                }
            }
        }
    }
}

// -------------------- layer-1 edge coefficients (one wave per dst node) --------------------
__global__ __launch_bounds__(256) void k_att1(
    const float* __restrict__ as1, const float* __restrict__ ad1,
    const int* __restrict__ rowptr, const int* __restrict__ col,
    float* __restrict__ ex1, float* __restrict__ rden1, int N)
{
    int wid = (int)(((unsigned)blockIdx.x * blockDim.x + threadIdx.x) >> 6);
    if (wid >= N) return;
    int lane = threadIdx.x & 63;
    int start = rowptr[wid], end = rowptr[wid + 1];
    const float4 ad = *(const float4*)(ad1 + (size_t)wid * 4);

    float den0 = 0.f, den1 = 0.f, den2 = 0.f, den3 = 0.f;
    for (int e = start + lane; e < end; e += 64) {
        int src = col[e];
        const float4 a = *(const float4*)(as1 + (size_t)src * 4);
        float e0 = __expf(lrelu02(a.x + ad.x));
        float e1 = __expf(lrelu02(a.y + ad.y));
        float e2 = __expf(lrelu02(a.z + ad.z));
        float e3 = __expf(lrelu02(a.w + ad.w));
        *(float4*)(ex1 + (size_t)e * 4) = make_float4(e0, e1, e2, e3);
        den0 += e0; den1 += e1; den2 += e2; den3 += e3;
    }
    #pragma unroll
    for (int m = 32; m >= 1; m >>= 1) {
        den0 += __shfl_xor(den0, m); den1 += __shfl_xor(den1, m);
        den2 += __shfl_xor(den2, m); den3 += __shfl_xor(den3, m);
    }
    if (lane == 0)
        *(float4*)(rden1 + (size_t)wid * 4) =
            make_float4(1.f / den0, 1.f / den1, 1.f / den2, 1.f / den3);
}

// -------------------- layer-1 aggregate: one wave per dst node, 8 gathers in flight ------
__global__ __launch_bounds__(256) void k_agg1(
    const unsigned short* __restrict__ h1, const float* __restrict__ ex1,
    const float* __restrict__ rden1, const int* __restrict__ rowptr,
    const int* __restrict__ col, const float* __restrict__ b1,
    float* __restrict__ out1, int N)
{
    int wid = (int)(((unsigned)blockIdx.x * blockDim.x + threadIdx.x) >> 6);
    if (wid >= N) return;
    int lane = threadIdx.x & 63;
    int head = lane >> 4;                       // channels {2*lane, 2*lane+1}
    float rden = rden1[wid * 4 + head];
    int start = rowptr[wid], end = rowptr[wid + 1];

    float acc0 = 0.f, acc1 = 0.f;
    for (int e = start; e < end; e += 8) {
        int   s[8];
        float cf[8];
        unsigned hv[8];
        #pragma unroll
        for (int j = 0; j < 8; ++j) {
            int ee = e + j;
            bool ok = ee < end;
            int es = ok ? ee : e;               // clamp to a valid edge
            s[j]  = col[es];
            cf[j] = ok ? ex1[(size_t)es * 4 + head] : 0.f;
        }
        #pragma unroll
        for (int j = 0; j < 8; ++j)
            hv[j] = *(const unsigned*)(h1 + (size_t)s[j] * 128 + lane * 2);
        #pragma unroll
        for (int j = 0; j < 8; ++j) {
            float coef = cf[j] * rden;
            acc0 = fmaf(coef, __uint_as_float(hv[j] << 16), acc0);
            acc1 = fmaf(coef, __uint_as_float(hv[j] & 0xffff0000u), acc1);
        }
    }
    int c0 = lane * 2;
    float o0 = acc0 + b1[c0];
    float o1 = acc1 + b1[c0 + 1];
    o0 = o0 > 0.f ? o0 : expm1f(o0);
    o1 = o1 > 0.f ? o1 : expm1f(o1);
    *(float2*)&out1[(size_t)wid * 128 + c0] = make_float2(o0, o1);
}

// -------------------- GEMM2: h2 = out1 @ W2, fused logits --------------------
__global__ __launch_bounds__(256) void k_gemm2(
    const float* __restrict__ in, const float* __restrict__ W,
    const float* __restrict__ attS, const float* __restrict__ attD,
    float* __restrict__ h2, float* __restrict__ as2, float* __restrict__ ad2, int N)
{
    __shared__ float Wl[128 * 16];
    __shared__ float xl[64][132];
    const int t = threadIdx.x;
    const int cg = t & 3;                 // 4 col-groups * 4 cols = 16
    const int rloc = t >> 2;              // 64 rows

    for (int i = t; i < 128 * 16 / 4; i += 256)
        ((float4*)Wl)[i] = ((const float4*)W)[i];
    float aSr[4], aDr[4];
    #pragma unroll
    for (int j = 0; j < 4; ++j) { aSr[j] = attS[cg * 4 + j]; aDr[j] = attD[cg * 4 + j]; }

    for (int r0 = blockIdx.x * 64; r0 < N; r0 += gridDim.x * 64) {
        __syncthreads();
        #pragma unroll
        for (int j = 0; j < 8; ++j) {
            int idx = t + j * 256;
            int rr = idx >> 5, cc = idx & 31;
            int r = r0 + rr;
            float4 v = make_float4(0.f, 0.f, 0.f, 0.f);
            if (r < N) v = ((const float4*)(in + (size_t)r * 128))[cc];
            *(float4*)&xl[rr][cc * 4] = v;
        }
        __syncthreads();

        float acc[4] = {0.f, 0.f, 0.f, 0.f};
        #pragma unroll 4
        for (int k = 0; k < 128; ++k) {
            float xv = xl[rloc][k];
            float4 wv = *(const float4*)&Wl[k * 16 + cg * 4];
            acc[0] = fmaf(xv, wv.x, acc[0]);
            acc[1] = fmaf(xv, wv.y, acc[1]);
            acc[2] = fmaf(xv, wv.z, acc[2]);
            acc[3] = fmaf(xv, wv.w, acc[3]);
        }
        int r = r0 + rloc;
        float s = acc[0]*aSr[0] + acc[1]*aSr[1] + acc[2]*aSr[2] + acc[3]*aSr[3];
        float d = acc[0]*aDr[0] + acc[1]*aDr[1] + acc[2]*aDr[2] + acc[3]*aDr[3];
        s += __shfl_xor(s, 1); s += __shfl_xor(s, 2);
        d += __shfl_xor(d, 1); d += __shfl_xor(d, 2);
        if (r < N) {
            *(float4*)&h2[(size_t)r * 16 + cg * 4] = make_float4(acc[0], acc[1], acc[2], acc[3]);
            if (cg == 0) { as2[r] = s; ad2[r] = d; }
        }
    }
}

// -------------------- layer-2 edge coefficients --------------------
__global__ __launch_bounds__(256) void k_att2(
    const float* __restrict__ as2, const float* __restrict__ ad2,
    const int* __restrict__ rowptr, const int* __restrict__ col,
    float* __restrict__ ex2, float* __restrict__ rden2, int N)
{
    int wid = (int)(((unsigned)blockIdx.x * blockDim.x + threadIdx.x) >> 6);
    if (wid >= N) return;
    int lane = threadIdx.x & 63;
    int start = rowptr[wid], end = rowptr[wid + 1];
    float adv = ad2[wid];
    float den = 0.f;
    for (int e = start + lane; e < end; e += 64) {
        float ev = __expf(lrelu02(as2[col[e]] + adv));
        ex2[e] = ev;
        den += ev;
    }
    #pragma unroll
    for (int m = 32; m >= 1; m >>= 1) den += __shfl_xor(den, m);
    if (lane == 0) rden2[wid] = 1.f / den;
}

// -------------------- layer-2 aggregate: 4 subgroups x unroll 4 = 16 gathers in flight ---
__global__ __launch_bounds__(256) void k_agg2(
    const float* __restrict__ h2, const float* __restrict__ ex2,
    const float* __restrict__ rden2, const int* __restrict__ rowptr,
    const int* __restrict__ col, const float* __restrict__ b2,
    float* __restrict__ out, int N)
{
    int wid = (int)(((unsigned)blockIdx.x * blockDim.x + threadIdx.x) >> 6);
    if (wid >= N) return;
    int lane = threadIdx.x & 63;
    int start = rowptr[wid], end = rowptr[wid + 1];
    float rden = rden2[wid];
    int sub = lane >> 4, c = lane & 15;
    float acc = 0.f;
    for (int e0 = start + sub; e0 < end; e0 += 16) {
        int   s[4];
        float cf[4];
        float hvv[4];
        #pragma unroll
        for (int j = 0; j < 4; ++j) {
            int ee = e0 + j * 4;
            bool ok = ee < end;
            int es = ok ? ee : e0;
            s[j]  = col[es];
            cf[j] = ok ? ex2[es] : 0.f;
        }
        #pragma unroll
        for (int j = 0; j < 4; ++j)
            hvv[j] = h2[(size_t)s[j] * 16 + c];
        #pragma unroll
        for (int j = 0; j < 4; ++j)
            acc = fmaf(cf[j] * rden, hvv[j], acc);
    }
    acc += __shfl_xor(acc, 16);
    acc += __shfl_xor(acc, 32);
    if (lane < 16) out[(size_t)wid * 16 + lane] = acc + b2[lane];
}

extern "C" void kernel_launch(void* const* d_in, const int* in_sizes, int n_in,
                              void* d_out, int out_size, void* d_ws, size_t ws_size,
                              hipStream_t stream)
{
    const float* x   = (const float*)d_in[0];
    const int*   ei  = (const int*)d_in[1];
    const float* W1  = (const float*)d_in[2];
    const float* aS1 = (const float*)d_in[3];
    const float* aD1 = (const float*)d_in[4];
    const float* b1  = (const float*)d_in[5];
    const float* W2  = (const float*)d_in[6];
    const float* aS2 = (const float*)d_in[7];
    const float* aD2 = (const float*)d_in[8];
    const float* b2  = (const float*)d_in[9];
    float* out = (float*)d_out;

    int N = in_sizes[0] / 128;
    int E = in_sizes[1] / 2;
    int ET = E + N;
    int nblk = (N + 2047) / 2048;   // scan blocks (<= 64)

    char* w = (char*)d_ws;
    auto alloc = [&](size_t bytes) -> void* {
        void* p = (void*)w;
        w += (bytes + 255) & ~(size_t)255;
        return p;
    };
    unsigned short* h1 = (unsigned short*)alloc((size_t)N * 128 * 2);   // bf16
    float* out1  = (float*)alloc((size_t)N * 128 * 4);
    float* as1   = (float*)alloc((size_t)N * 4 * 4);
    float* ad1   = (float*)alloc((size_t)N * 4 * 4);
    float* rden1 = (float*)alloc((size_t)N * 4 * 4);
    float* h2    = (float*)alloc((size_t)N * 16 * 4);
    float* as2v  = (float*)alloc((size_t)N * 4);
    float* ad2v  = (float*)alloc((size_t)N * 4);
    float* rden2 = (float*)alloc((size_t)N * 4);
    float* ex1   = (float*)alloc((size_t)ET * 4 * 4);
    float* ex2   = (float*)alloc((size_t)ET * 4);
    int* deg     = (int*)alloc((size_t)N * 4);
    int* rowptr  = (int*)alloc((size_t)(N + 1) * 4);
    int* fillc   = (int*)alloc((size_t)N * 4);
    int* col     = (int*)alloc((size_t)ET * 4);
    int* bsum    = (int*)alloc(64 * 4);

    hipMemsetAsync(deg, 0, (size_t)N * 4, stream);
    hipMemsetAsync(fillc, 0, (size_t)N * 4, stream);

    const int tb = 256;
    k_deg       <<<(ET + tb - 1) / tb, tb, 0, stream>>>(ei, deg, E, N);
    k_scan_local<<<nblk, 256, 0, stream>>>(deg, rowptr, bsum, N);
    k_scan_bsum <<<1, 64, 0, stream>>>(bsum, nblk);
    k_scan_add  <<<nblk, 256, 0, stream>>>(rowptr, bsum, N, ET);
    k_fill      <<<(ET + tb - 1) / tb, tb, 0, stream>>>(ei, rowptr, fillc, col, E, N);

    k_gemm1<<<512, 256, 0, stream>>>(x, W1, aS1, aD1, h1, as1, ad1, N);
    k_att1 <<<(N + 3) / 4, tb, 0, stream>>>(as1, ad1, rowptr, col, ex1, rden1, N);
    k_agg1 <<<(N + 3) / 4, tb, 0, stream>>>(h1, ex1, rden1, rowptr, col, b1, out1, N);
    k_gemm2<<<512, 256, 0, stream>>>(out1, W2, aS2, aD2, h2, as2v, ad2v, N);
    k_att2 <<<(N + 3) / 4, tb, 0, stream>>>(as2v, ad2v, rowptr, col, ex2, rden2, N);
    k_agg2 <<<(N + 3) / 4, tb, 0, stream>>>(h2, ex2, rden2, rowptr, col, b2, out, N);
}

// Round 5
// 225.550 us; speedup vs baseline: 1.7539x; 1.0360x over previous
//
#include <hip/hip_runtime.h>

typedef __attribute__((ext_vector_type(8))) short short8;
typedef __attribute__((ext_vector_type(4))) float f32x4;

__device__ __forceinline__ float lrelu02(float a) { return a > 0.0f ? a : 0.2f * a; }

__device__ __forceinline__ unsigned bf16rne(float f) {
    unsigned u = __float_as_uint(f);
    return (u + 0x7fffu + ((u >> 16) & 1u)) >> 16;
}

#define NRANGE 8
#define NCHUNK 128

// -------------------- CSR build (XCD-range-partitioned) --------------------
__global__ __launch_bounds__(256) void k_deg(const int* __restrict__ ei,
                                             int* __restrict__ deg, int E, int N) {
    int r = blockIdx.x & 7, c = blockIdx.x >> 3;
    int rw = (N + NRANGE - 1) / NRANGE;
    int lo = r * rw, hi = min(lo + rw, N);
    int ET = E + N;
    int per = (ET + NCHUNK - 1) / NCHUNK;
    int e1 = min(c * per + per, ET);
    for (int e = c * per + threadIdx.x; e < e1; e += blockDim.x) {
        int d = (e < E) ? __builtin_nontemporal_load(ei + E + e) : (e - E);
        if (d >= lo && d < hi) atomicAdd(&deg[d], 1);
    }
}

// 3-phase hierarchical exclusive scan over deg[N] -> rowptr[N+1]
__global__ __launch_bounds__(256) void k_scan_local(
    const int* __restrict__ deg, int* __restrict__ rowptr, int* __restrict__ bsum, int N)
{
    const int t = threadIdx.x;
    const int base = blockIdx.x * 2048 + t * 8;
    int v[8];
    int s = 0;
    #pragma unroll
    for (int j = 0; j < 8; ++j) {
        int idx = base + j;
        v[j] = (idx < N) ? deg[idx] : 0;
        s += v[j];
    }
    __shared__ int ts[256];
    ts[t] = s;
    __syncthreads();
    #pragma unroll
    for (int off = 1; off < 256; off <<= 1) {
        int u = (t >= off) ? ts[t - off] : 0;
        __syncthreads();
        ts[t] += u;
        __syncthreads();
    }
    int ex = (t == 0) ? 0 : ts[t - 1];
    #pragma unroll
    for (int j = 0; j < 8; ++j) {
        int idx = base + j;
        if (idx < N) rowptr[idx] = ex;
        ex += v[j];
    }
    if (t == 255) bsum[blockIdx.x] = ts[255];
}

__global__ void k_scan_bsum(int* __restrict__ bsum, int nblk) {
    int t = threadIdx.x;
    int v = (t < nblk) ? bsum[t] : 0;
    int inc = v;
    #pragma unroll
    for (int off = 1; off < 64; off <<= 1) {
        int u = __shfl_up(inc, off);
        if (t >= off) inc += u;
    }
    if (t < nblk) bsum[t] = inc - v;
}

__global__ __launch_bounds__(256) void k_scan_add(
    int* __restrict__ rowptr, const int* __restrict__ bsum, int N, int ET)
{
    const int t = threadIdx.x;
    const int base = blockIdx.x * 2048 + t * 8;
    int off = bsum[blockIdx.x];
    #pragma unroll
    for (int j = 0; j < 8; ++j) {
        int idx = base + j;
        if (idx < N) rowptr[idx] += off;
    }
    if (blockIdx.x == 0 && t == 0) rowptr[N] = ET;
}

__global__ __launch_bounds__(256) void k_fill(const int* __restrict__ ei,
                                              const int* __restrict__ rowptr,
                                              int* __restrict__ fillc, int* __restrict__ col,
                                              int E, int N) {
    int r = blockIdx.x & 7, c = blockIdx.x >> 3;
    int rw = (N + NRANGE - 1) / NRANGE;
    int lo = r * rw, hi = min(lo + rw, N);
    int ET = E + N;
    int per = (ET + NCHUNK - 1) / NCHUNK;
    int e1 = min(c * per + per, ET);
    for (int e = c * per + threadIdx.x; e < e1; e += blockDim.x) {
        int d = (e < E) ? __builtin_nontemporal_load(ei + E + e) : (e - E);
        if (d >= lo && d < hi) {
            int s = (e < E) ? __builtin_nontemporal_load(ei + e) : d;
            int p = rowptr[d] + atomicAdd(&fillc[d], 1);
            col[p] = s;
        }
    }
}

// -------------------- GEMM1 (MFMA bf16): h1(bf16) = x @ W1, fused logits ----------------
// block = 256 thr (4 waves), 64 rows; wave w: rows w*16..w*16+15, all 128 cols.
// LDS: Wt[n][k] bf16 (32 KB) + xs[m][k] bf16 (16 KB), both XOR-swizzled (^((row&7)<<4)).
__global__ __launch_bounds__(256) void k_gemm1(
    const float* __restrict__ x, const float* __restrict__ W,
    const float* __restrict__ attS, const float* __restrict__ attD,
    unsigned short* __restrict__ h1, float* __restrict__ as1, float* __restrict__ ad1, int N)
{
    __shared__ unsigned short Wt[128 * 128];   // [n][k], 32 KB
    __shared__ unsigned short xs[64 * 128];    // [m][k], 16 KB (reused for h-tile out)

    const int t = threadIdx.x;
    const int lane = t & 63;
    const int wv = t >> 6;
    const int ln = lane & 15;
    const int lg = lane >> 4;
    const int r0 = blockIdx.x * 64;

    // stage W transposed -> Wt[n][k] bf16, swizzled
    {
        int kbase = t >> 5, n0 = (t & 31) * 4;
        for (int it = 0; it < 16; ++it) {
            int k = kbase + it * 8;
            float4 v = *(const float4*)&W[(size_t)k * 128 + n0];
            float vv[4] = {v.x, v.y, v.z, v.w};
            #pragma unroll
            for (int j = 0; j < 4; ++j) {
                int n = n0 + j;
                int byteo = n * 256 + ((k * 2) ^ ((n & 7) << 4));
                *(unsigned short*)((char*)Wt + byteo) = (unsigned short)bf16rne(vv[j]);
            }
        }
    }
    // stage x tile -> xs[m][k] bf16, swizzled
    {
        int mbase = t >> 5, k0 = (t & 31) * 4;
        for (int it = 0; it < 8; ++it) {
            int m = mbase + it * 8;
            int rr = r0 + m;
            float4 v = make_float4(0.f, 0.f, 0.f, 0.f);
            if (rr < N) v = *(const float4*)&x[(size_t)rr * 128 + k0];
            unsigned lo = bf16rne(v.x) | (bf16rne(v.y) << 16);
            unsigned hi = bf16rne(v.z) | (bf16rne(v.w) << 16);
            int byteo = m * 256 + ((k0 * 2) ^ ((m & 7) << 4));
            *(uint2*)((char*)xs + byteo) = make_uint2(lo, hi);
        }
    }
    __syncthreads();

    f32x4 acc[8];
    #pragma unroll
    for (int i = 0; i < 8; ++i) acc[i] = (f32x4)(0.f);

    #pragma unroll
    for (int kk = 0; kk < 4; ++kk) {
        int kb = (kk * 32 + lg * 8) * 2;                    // byte offset of 8 contiguous k
        int am = wv * 16 + ln;
        short8 a = *(const short8*)((char*)xs + am * 256 + (kb ^ ((am & 7) << 4)));
        #pragma unroll
        for (int tile = 0; tile < 8; ++tile) {
            int n = tile * 16 + ln;
            short8 b = *(const short8*)((char*)Wt + n * 256 + (kb ^ ((n & 7) << 4)));
            acc[tile] = __builtin_amdgcn_mfma_f32_16x16x32_bf16(a, b, acc[tile], 0, 0, 0);
        }
    }

    // fused logits: D layout col = ln, row = wv*16 + lg*4 + r
    float aSt[8], aDt[8];
    #pragma unroll
    for (int tile = 0; tile < 8; ++tile) {
        aSt[tile] = attS[tile * 16 + ln];
        aDt[tile] = attD[tile * 16 + ln];
    }
    #pragma unroll
    for (int r = 0; r < 4; ++r) {
        int row = r0 + wv * 16 + lg * 4 + r;
        #pragma unroll
        for (int h = 0; h < 4; ++h) {
            float s = acc[2*h][r] * aSt[2*h] + acc[2*h+1][r] * aSt[2*h+1];
            float d = acc[2*h][r] * aDt[2*h] + acc[2*h+1][r] * aDt[2*h+1];
            s += __shfl_xor(s, 1); s += __shfl_xor(s, 2); s += __shfl_xor(s, 4); s += __shfl_xor(s, 8);
            d += __shfl_xor(d, 1); d += __shfl_xor(d, 2); d += __shfl_xor(d, 4); d += __shfl_xor(d, 8);
            if (ln == h * 4 + r && row < N) {
                as1[row * 4 + h] = s;
                ad1[row * 4 + h] = d;
            }
        }
    }

    // write h1 via LDS transpose for coalesced global stores (reuse xs, linear layout)
    __syncthreads();
    #pragma unroll
    for (int tile = 0; tile < 8; ++tile) {
        #pragma unroll
        for (int r = 0; r < 4; ++r) {
            int m = wv * 16 + lg * 4 + r;
            xs[m * 128 + tile * 16 + ln] = (unsigned short)bf16rne(acc[tile][r]);
        }
    }
    __syncthreads();
    #pragma unroll
    for (int it = 0; it < 4; ++it) {
        int idx = t + it * 256;                 // 1024 x 16B = 16 KB
        int m = idx >> 4, o = idx & 15;
        if (r0 + m < N)
            *(uint4*)((char*)(h1 + (size_t)(r0 + m) * 128) + o * 16) =
                *(const uint4*)((const char*)(xs + m * 128) + o * 16);
    }
}

// -------------------- layer-1 edge coefficients (one wave per dst node) --------------------
__global__ __launch_bounds__(256) void k_att1(
    const float* __restrict__ as1, const float* __restrict__ ad1,
    const int* __restrict__ rowptr, const int* __restrict__ col,
    float* __restrict__ ex1, float* __restrict__ rden1, int N)
{
    int wid = (int)(((unsigned)blockIdx.x * blockDim.x + threadIdx.x) >> 6);
    if (wid >= N) return;
    int lane = threadIdx.x & 63;
    int start = rowptr[wid], end = rowptr[wid + 1];
    const float4 ad = *(const float4*)(ad1 + (size_t)wid * 4);

    float den0 = 0.f, den1 = 0.f, den2 = 0.f, den3 = 0.f;
    for (int e = start + lane; e < end; e += 64) {
        int src = col[e];
        const float4 a = *(const float4*)(as1 + (size_t)src * 4);
        float e0 = __expf(lrelu02(a.x + ad.x));
        float e1 = __expf(lrelu02(a.y + ad.y));
        float e2 = __expf(lrelu02(a.z + ad.z));
        float e3 = __expf(lrelu02(a.w + ad.w));
        *(float4*)(ex1 + (size_t)e * 4) = make_float4(e0, e1, e2, e3);
        den0 += e0; den1 += e1; den2 += e2; den3 += e3;
    }
    #pragma unroll
    for (int m = 32; m >= 1; m >>= 1) {
        den0 += __shfl_xor(den0, m); den1 += __shfl_xor(den1, m);
        den2 += __shfl_xor(den2, m); den3 += __shfl_xor(den3, m);
    }
    if (lane == 0)
        *(float4*)(rden1 + (size_t)wid * 4) =
            make_float4(1.f / den0, 1.f / den1, 1.f / den2, 1.f / den3);
}

// -------------------- layer-1 aggregate: one wave per dst node, 8 gathers in flight ------
__global__ __launch_bounds__(256) void k_agg1(
    const unsigned short* __restrict__ h1, const float* __restrict__ ex1,
    const float* __restrict__ rden1, const int* __restrict__ rowptr,
    const int* __restrict__ col, const float* __restrict__ b1,
    float* __restrict__ out1, int N)
{
    int wid = (int)(((unsigned)blockIdx.x * blockDim.x + threadIdx.x) >> 6);
    if (wid >= N) return;
    int lane = threadIdx.x & 63;
    int head = lane >> 4;
    float rden = rden1[wid * 4 + head];
    int start = rowptr[wid], end = rowptr[wid + 1];

    float acc0 = 0.f, acc1 = 0.f;
    for (int e = start; e < end; e += 8) {
        int   s[8];
        float cf[8];
        unsigned hv[8];
        #pragma unroll
        for (int j = 0; j < 8; ++j) {
            int ee = e + j;
            bool ok = ee < end;
            int es = ok ? ee : e;
            s[j]  = col[es];
            cf[j] = ok ? ex1[(size_t)es * 4 + head] : 0.f;
        }
        #pragma unroll
        for (int j = 0; j < 8; ++j)
            hv[j] = *(const unsigned*)(h1 + (size_t)s[j] * 128 + lane * 2);
        #pragma unroll
        for (int j = 0; j < 8; ++j) {
            float coef = cf[j] * rden;
            acc0 = fmaf(coef, __uint_as_float(hv[j] << 16), acc0);
            acc1 = fmaf(coef, __uint_as_float(hv[j] & 0xffff0000u), acc1);
        }
    }
    int c0 = lane * 2;
    float o0 = acc0 + b1[c0];
    float o1 = acc1 + b1[c0 + 1];
    o0 = o0 > 0.f ? o0 : expm1f(o0);
    o1 = o1 > 0.f ? o1 : expm1f(o1);
    *(float2*)&out1[(size_t)wid * 128 + c0] = make_float2(o0, o1);
}

// -------------------- GEMM2: h2 = out1 @ W2, fused logits --------------------
__global__ __launch_bounds__(256) void k_gemm2(
    const float* __restrict__ in, const float* __restrict__ W,
    const float* __restrict__ attS, const float* __restrict__ attD,
    float* __restrict__ h2, float* __restrict__ as2, float* __restrict__ ad2, int N)
{
    __shared__ float Wl[128 * 16];
    __shared__ float xl[64][132];
    const int t = threadIdx.x;
    const int cg = t & 3;
    const int rloc = t >> 2;

    for (int i = t; i < 128 * 16 / 4; i += 256)
        ((float4*)Wl)[i] = ((const float4*)W)[i];
    float aSr[4], aDr[4];
    #pragma unroll
    for (int j = 0; j < 4; ++j) { aSr[j] = attS[cg * 4 + j]; aDr[j] = attD[cg * 4 + j]; }

    for (int r0 = blockIdx.x * 64; r0 < N; r0 += gridDim.x * 64) {
        __syncthreads();
        #pragma unroll
        for (int j = 0; j < 8; ++j) {
            int idx = t + j * 256;
            int rr = idx >> 5, cc = idx & 31;
            int r = r0 + rr;
            float4 v = make_float4(0.f, 0.f, 0.f, 0.f);
            if (r < N) v = ((const float4*)(in + (size_t)r * 128))[cc];
            *(float4*)&xl[rr][cc * 4] = v;
        }
        __syncthreads();

        float acc[4] = {0.f, 0.f, 0.f, 0.f};
        #pragma unroll 4
        for (int k = 0; k < 128; ++k) {
            float xv = xl[rloc][k];
            float4 wv = *(const float4*)&Wl[k * 16 + cg * 4];
            acc[0] = fmaf(xv, wv.x, acc[0]);
            acc[1] = fmaf(xv, wv.y, acc[1]);
            acc[2] = fmaf(xv, wv.z, acc[2]);
            acc[3] = fmaf(xv, wv.w, acc[3]);
        }
        int r = r0 + rloc;
        float s = acc[0]*aSr[0] + acc[1]*aSr[1] + acc[2]*aSr[2] + acc[3]*aSr[3];
        float d = acc[0]*aDr[0] + acc[1]*aDr[1] + acc[2]*aDr[2] + acc[3]*aDr[3];
        s += __shfl_xor(s, 1); s += __shfl_xor(s, 2);
        d += __shfl_xor(d, 1); d += __shfl_xor(d, 2);
        if (r < N) {
            *(float4*)&h2[(size_t)r * 16 + cg * 4] = make_float4(acc[0], acc[1], acc[2], acc[3]);
            if (cg == 0) { as2[r] = s; ad2[r] = d; }
        }
    }
}

// -------------------- layer-2 edge coefficients --------------------
__global__ __launch_bounds__(256) void k_att2(
    const float* __restrict__ as2, const float* __restrict__ ad2,
    const int* __restrict__ rowptr, const int* __restrict__ col,
    float* __restrict__ ex2, float* __restrict__ rden2, int N)
{
    int wid = (int)(((unsigned)blockIdx.x * blockDim.x + threadIdx.x) >> 6);
    if (wid >= N) return;
    int lane = threadIdx.x & 63;
    int start = rowptr[wid], end = rowptr[wid + 1];
    float adv = ad2[wid];
    float den = 0.f;
    for (int e = start + lane; e < end; e += 64) {
        float ev = __expf(lrelu02(as2[col[e]] + adv));
        ex2[e] = ev;
        den += ev;
    }
    #pragma unroll
    for (int m = 32; m >= 1; m >>= 1) den += __shfl_xor(den, m);
    if (lane == 0) rden2[wid] = 1.f / den;
}

// -------------------- layer-2 aggregate --------------------
__global__ __launch_bounds__(256) void k_agg2(
    const float* __restrict__ h2, const float* __restrict__ ex2,
    const float* __restrict__ rden2, const int* __restrict__ rowptr,
    const int* __restrict__ col, const float* __restrict__ b2,
    float* __restrict__ out, int N)
{
    int wid = (int)(((unsigned)blockIdx.x * blockDim.x + threadIdx.x) >> 6);
    if (wid >= N) return;
    int lane = threadIdx.x & 63;
    int start = rowptr[wid], end = rowptr[wid + 1];
    float rden = rden2[wid];
    int sub = lane >> 4, c = lane & 15;
    float acc = 0.f;
    for (int e0 = start + sub; e0 < end; e0 += 16) {
        int   s[4];
        float cf[4];
        float hvv[4];
        #pragma unroll
        for (int j = 0; j < 4; ++j) {
            int ee = e0 + j * 4;
            bool ok = ee < end;
            int es = ok ? ee : e0;
            s[j]  = col[es];
            cf[j] = ok ? ex2[es] : 0.f;
        }
        #pragma unroll
        for (int j = 0; j < 4; ++j)
            hvv[j] = h2[(size_t)s[j] * 16 + c];
        #pragma unroll
        for (int j = 0; j < 4; ++j)
            acc = fmaf(cf[j] * rden, hvv[j], acc);
    }
    acc += __shfl_xor(acc, 16);
    acc += __shfl_xor(acc, 32);
    if (lane < 16) out[(size_t)wid * 16 + lane] = acc + b2[lane];
}

extern "C" void kernel_launch(void* const* d_in, const int* in_sizes, int n_in,
                              void* d_out, int out_size, void* d_ws, size_t ws_size,
                              hipStream_t stream)
{
    const float* x   = (const float*)d_in[0];
    const int*   ei  = (const int*)d_in[1];
    const float* W1  = (const float*)d_in[2];
    const float* aS1 = (const float*)d_in[3];
    const float* aD1 = (const float*)d_in[4];
    const float* b1  = (const float*)d_in[5];
    const float* W2  = (const float*)d_in[6];
    const float* aS2 = (const float*)d_in[7];
    const float* aD2 = (const float*)d_in[8];
    const float* b2  = (const float*)d_in[9];
    float* out = (float*)d_out;

    int N = in_sizes[0] / 128;
    int E = in_sizes[1] / 2;
    int ET = E + N;
    int nblk = (N + 2047) / 2048;

    char* w = (char*)d_ws;
    auto alloc = [&](size_t bytes) -> void* {
        void* p = (void*)w;
        w += (bytes + 255) & ~(size_t)255;
        return p;
    };
    unsigned short* h1 = (unsigned short*)alloc((size_t)N * 128 * 2);
    float* out1  = (float*)alloc((size_t)N * 128 * 4);
    float* as1   = (float*)alloc((size_t)N * 4 * 4);
    float* ad1   = (float*)alloc((size_t)N * 4 * 4);
    float* rden1 = (float*)alloc((size_t)N * 4 * 4);
    float* h2    = (float*)alloc((size_t)N * 16 * 4);
    float* as2v  = (float*)alloc((size_t)N * 4);
    float* ad2v  = (float*)alloc((size_t)N * 4);
    float* rden2 = (float*)alloc((size_t)N * 4);
    float* ex1   = (float*)alloc((size_t)ET * 4 * 4);
    float* ex2   = (float*)alloc((size_t)ET * 4);
    int* deg     = (int*)alloc((size_t)N * 4);
    int* rowptr  = (int*)alloc((size_t)(N + 1) * 4);
    int* fillc   = (int*)alloc((size_t)N * 4);
    int* col     = (int*)alloc((size_t)ET * 4);
    int* bsum    = (int*)alloc(64 * 4);

    hipMemsetAsync(deg, 0, (size_t)N * 4, stream);
    hipMemsetAsync(fillc, 0, (size_t)N * 4, stream);

    const int tb = 256;
    k_deg       <<<NRANGE * NCHUNK, tb, 0, stream>>>(ei, deg, E, N);
    k_scan_local<<<nblk, 256, 0, stream>>>(deg, rowptr, bsum, N);
    k_scan_bsum <<<1, 64, 0, stream>>>(bsum, nblk);
    k_scan_add  <<<nblk, 256, 0, stream>>>(rowptr, bsum, N, ET);
    k_fill      <<<NRANGE * NCHUNK, tb, 0, stream>>>(ei, rowptr, fillc, col, E, N);

    k_gemm1<<<(N + 63) / 64, 256, 0, stream>>>(x, W1, aS1, aD1, h1, as1, ad1, N);
    k_att1 <<<(N + 3) / 4, tb, 0, stream>>>(as1, ad1, rowptr, col, ex1, rden1, N);
    k_agg1 <<<(N + 3) / 4, tb, 0, stream>>>(h1, ex1, rden1, rowptr, col, b1, out1, N);
    k_gemm2<<<512, 256, 0, stream>>>(out1, W2, aS2, aD2, h2, as2v, ad2v, N);
    k_att2 <<<(N + 3) / 4, tb, 0, stream>>>(as2v, ad2v, rowptr, col, ex2, rden2, N);
    k_agg2 <<<(N + 3) / 4, tb, 0, stream>>>(h2, ex2, rden2, rowptr, col, b2, out, N);
}

// Round 6
// 186.328 us; speedup vs baseline: 2.1231x; 1.2105x over previous
//
#include <hip/hip_runtime.h>

typedef __attribute__((ext_vector_type(8))) short short8;
typedef __attribute__((ext_vector_type(4))) float f32x4;

__device__ __forceinline__ float lrelu02(float a) { return a > 0.0f ? a : 0.2f * a; }

__device__ __forceinline__ unsigned bf16rne(float f) {
    unsigned u = __float_as_uint(f);
    return (u + 0x7fffu + ((u >> 16) & 1u)) >> 16;
}

// -------------------- CSR build: rank pass (the ONLY atomic pass) --------------------
__global__ __launch_bounds__(256) void k_rank(const int* __restrict__ ei, int* __restrict__ deg,
                                              int* __restrict__ rank, int E, int N) {
    int tid = blockIdx.x * blockDim.x + threadIdx.x;
    int nthr = gridDim.x * blockDim.x;
    int E4 = E & ~3;
    for (int b = tid * 4; b < E4; b += nthr * 4) {
        int4 d = *(const int4*)(ei + E + b);
        int4 r;
        r.x = atomicAdd(&deg[d.x], 1);
        r.y = atomicAdd(&deg[d.y], 1);
        r.z = atomicAdd(&deg[d.z], 1);
        r.w = atomicAdd(&deg[d.w], 1);
        *(int4*)(rank + b) = r;
    }
    for (int e = E4 + tid; e < E; e += nthr)
        rank[e] = atomicAdd(&deg[ei[E + e]], 1);
    for (int i = tid; i < N; i += nthr)
        rank[E + i] = atomicAdd(&deg[i], 1);            // self loops
}

// 3-phase hierarchical exclusive scan over deg[N] -> rowptr[N+1]
__global__ __launch_bounds__(256) void k_scan_local(
    const int* __restrict__ deg, int* __restrict__ rowptr, int* __restrict__ bsum, int N)
{
    const int t = threadIdx.x;
    const int base = blockIdx.x * 2048 + t * 8;
    int v[8];
    int s = 0;
    #pragma unroll
    for (int j = 0; j < 8; ++j) {
        int idx = base + j;
        v[j] = (idx < N) ? deg[idx] : 0;
        s += v[j];
    }
    __shared__ int ts[256];
    ts[t] = s;
    __syncthreads();
    #pragma unroll
    for (int off = 1; off < 256; off <<= 1) {
        int u = (t >= off) ? ts[t - off] : 0;
        __syncthreads();
        ts[t] += u;
        __syncthreads();
    }
    int ex = (t == 0) ? 0 : ts[t - 1];
    #pragma unroll
    for (int j = 0; j < 8; ++j) {
        int idx = base + j;
        if (idx < N) rowptr[idx] = ex;
        ex += v[j];
    }
    if (t == 255) bsum[blockIdx.x] = ts[255];
}

__global__ void k_scan_bsum(int* __restrict__ bsum, int nblk) {
    int t = threadIdx.x;
    int v = (t < nblk) ? bsum[t] : 0;
    int inc = v;
    #pragma unroll
    for (int off = 1; off < 64; off <<= 1) {
        int u = __shfl_up(inc, off);
        if (t >= off) inc += u;
    }
    if (t < nblk) bsum[t] = inc - v;
}

__global__ __launch_bounds__(256) void k_scan_add(
    int* __restrict__ rowptr, const int* __restrict__ bsum, int N, int ET)
{
    const int t = threadIdx.x;
    const int base = blockIdx.x * 2048 + t * 8;
    int off = bsum[blockIdx.x];
    #pragma unroll
    for (int j = 0; j < 8; ++j) {
        int idx = base + j;
        if (idx < N) rowptr[idx] += off;
    }
    if (blockIdx.x == 0 && t == 0) rowptr[N] = ET;
}

// -------------------- CSR fill: atomic-free gather/scatter --------------------
__global__ __launch_bounds__(256) void k_fill2(const int* __restrict__ ei,
                                               const int* __restrict__ rank,
                                               const int* __restrict__ rowptr,
                                               int* __restrict__ col, int E, int N) {
    int tid = blockIdx.x * blockDim.x + threadIdx.x;
    int nthr = gridDim.x * blockDim.x;
    int E4 = E & ~3;
    for (int b = tid * 4; b < E4; b += nthr * 4) {
        int4 d = *(const int4*)(ei + E + b);
        int4 s = *(const int4*)(ei + b);
        int4 r = *(const int4*)(rank + b);
        int p0 = rowptr[d.x] + r.x;
        int p1 = rowptr[d.y] + r.y;
        int p2 = rowptr[d.z] + r.z;
        int p3 = rowptr[d.w] + r.w;
        col[p0] = s.x;
        col[p1] = s.y;
        col[p2] = s.z;
        col[p3] = s.w;
    }
    for (int e = E4 + tid; e < E; e += nthr)
        col[rowptr[ei[E + e]] + rank[e]] = ei[e];
    for (int i = tid; i < N; i += nthr)
        col[rowptr[i] + rank[E + i]] = i;               // self loops
}

// -------------------- GEMM1 (MFMA bf16): h1(bf16) = x @ W1, fused logits ----------------
__global__ __launch_bounds__(256) void k_gemm1(
    const float* __restrict__ x, const float* __restrict__ W,
    const float* __restrict__ attS, const float* __restrict__ attD,
    unsigned short* __restrict__ h1, float* __restrict__ as1, float* __restrict__ ad1, int N)
{
    __shared__ unsigned short Wt[128 * 128];   // [n][k], 32 KB, swizzled
    __shared__ unsigned short xs[64 * 128];    // [m][k], 16 KB, swizzled (reused for out)

    const int t = threadIdx.x;
    const int lane = t & 63;
    const int wv = t >> 6;
    const int ln = lane & 15;
    const int lg = lane >> 4;
    const int r0 = blockIdx.x * 64;

    {
        int kbase = t >> 5, n0 = (t & 31) * 4;
        for (int it = 0; it < 16; ++it) {
            int k = kbase + it * 8;
            float4 v = *(const float4*)&W[(size_t)k * 128 + n0];
            float vv[4] = {v.x, v.y, v.z, v.w};
            #pragma unroll
            for (int j = 0; j < 4; ++j) {
                int n = n0 + j;
                int byteo = n * 256 + ((k * 2) ^ ((n & 7) << 4));
                *(unsigned short*)((char*)Wt + byteo) = (unsigned short)bf16rne(vv[j]);
            }
        }
    }
    {
        int mbase = t >> 5, k0 = (t & 31) * 4;
        for (int it = 0; it < 8; ++it) {
            int m = mbase + it * 8;
            int rr = r0 + m;
            float4 v = make_float4(0.f, 0.f, 0.f, 0.f);
            if (rr < N) v = *(const float4*)&x[(size_t)rr * 128 + k0];
            unsigned lo = bf16rne(v.x) | (bf16rne(v.y) << 16);
            unsigned hi = bf16rne(v.z) | (bf16rne(v.w) << 16);
            int byteo = m * 256 + ((k0 * 2) ^ ((m & 7) << 4));
            *(uint2*)((char*)xs + byteo) = make_uint2(lo, hi);
        }
    }
    __syncthreads();

    f32x4 acc[8];
    #pragma unroll
    for (int i = 0; i < 8; ++i) acc[i] = (f32x4)(0.f);

    #pragma unroll
    for (int kk = 0; kk < 4; ++kk) {
        int kb = (kk * 32 + lg * 8) * 2;
        int am = wv * 16 + ln;
        short8 a = *(const short8*)((char*)xs + am * 256 + (kb ^ ((am & 7) << 4)));
        #pragma unroll
        for (int tile = 0; tile < 8; ++tile) {
            int n = tile * 16 + ln;
            short8 b = *(const short8*)((char*)Wt + n * 256 + (kb ^ ((n & 7) << 4)));
            acc[tile] = __builtin_amdgcn_mfma_f32_16x16x32_bf16(a, b, acc[tile], 0, 0, 0);
        }
    }

    float aSt[8], aDt[8];
    #pragma unroll
    for (int tile = 0; tile < 8; ++tile) {
        aSt[tile] = attS[tile * 16 + ln];
        aDt[tile] = attD[tile * 16 + ln];
    }
    #pragma unroll
    for (int r = 0; r < 4; ++r) {
        int row = r0 + wv * 16 + lg * 4 + r;
        #pragma unroll
        for (int h = 0; h < 4; ++h) {
            float s = acc[2*h][r] * aSt[2*h] + acc[2*h+1][r] * aSt[2*h+1];
            float d = acc[2*h][r] * aDt[2*h] + acc[2*h+1][r] * aDt[2*h+1];
            s += __shfl_xor(s, 1); s += __shfl_xor(s, 2); s += __shfl_xor(s, 4); s += __shfl_xor(s, 8);
            d += __shfl_xor(d, 1); d += __shfl_xor(d, 2); d += __shfl_xor(d, 4); d += __shfl_xor(d, 8);
            if (ln == h * 4 + r && row < N) {
                as1[row * 4 + h] = s;
                ad1[row * 4 + h] = d;
            }
        }
    }

    __syncthreads();
    #pragma unroll
    for (int tile = 0; tile < 8; ++tile) {
        #pragma unroll
        for (int r = 0; r < 4; ++r) {
            int m = wv * 16 + lg * 4 + r;
            xs[m * 128 + tile * 16 + ln] = (unsigned short)bf16rne(acc[tile][r]);
        }
    }
    __syncthreads();
    #pragma unroll
    for (int it = 0; it < 4; ++it) {
        int idx = t + it * 256;
        int m = idx >> 4, o = idx & 15;
        if (r0 + m < N)
            *(uint4*)((char*)(h1 + (size_t)(r0 + m) * 128) + o * 16) =
                *(const uint4*)((const char*)(xs + m * 128) + o * 16);
    }
}

// -------------------- layer-1 edge coefficients (one wave per dst node) --------------------
__global__ __launch_bounds__(256) void k_att1(
    const float* __restrict__ as1, const float* __restrict__ ad1,
    const int* __restrict__ rowptr, const int* __restrict__ col,
    float* __restrict__ ex1, float* __restrict__ rden1, int N)
{
    int wid = (int)(((unsigned)blockIdx.x * blockDim.x + threadIdx.x) >> 6);
    if (wid >= N) return;
    int lane = threadIdx.x & 63;
    int start = rowptr[wid], end = rowptr[wid + 1];
    const float4 ad = *(const float4*)(ad1 + (size_t)wid * 4);

    float den0 = 0.f, den1 = 0.f, den2 = 0.f, den3 = 0.f;
    for (int e = start + lane; e < end; e += 64) {
        int src = col[e];
        const float4 a = *(const float4*)(as1 + (size_t)src * 4);
        float e0 = __expf(lrelu02(a.x + ad.x));
        float e1 = __expf(lrelu02(a.y + ad.y));
        float e2 = __expf(lrelu02(a.z + ad.z));
        float e3 = __expf(lrelu02(a.w + ad.w));
        *(float4*)(ex1 + (size_t)e * 4) = make_float4(e0, e1, e2, e3);
        den0 += e0; den1 += e1; den2 += e2; den3 += e3;
    }
    #pragma unroll
    for (int m = 32; m >= 1; m >>= 1) {
        den0 += __shfl_xor(den0, m); den1 += __shfl_xor(den1, m);
        den2 += __shfl_xor(den2, m); den3 += __shfl_xor(den3, m);
    }
    if (lane == 0)
        *(float4*)(rden1 + (size_t)wid * 4) =
            make_float4(1.f / den0, 1.f / den1, 1.f / den2, 1.f / den3);
}

// -------------------- layer-1 aggregate: one wave per dst, 8 gathers in flight; bf16 out --
__global__ __launch_bounds__(256) void k_agg1(
    const unsigned short* __restrict__ h1, const float* __restrict__ ex1,
    const float* __restrict__ rden1, const int* __restrict__ rowptr,
    const int* __restrict__ col, const float* __restrict__ b1,
    unsigned short* __restrict__ out1, int N)
{
    int wid = (int)(((unsigned)blockIdx.x * blockDim.x + threadIdx.x) >> 6);
    if (wid >= N) return;
    int lane = threadIdx.x & 63;
    int head = lane >> 4;
    float rden = rden1[wid * 4 + head];
    int start = rowptr[wid], end = rowptr[wid + 1];

    float acc0 = 0.f, acc1 = 0.f;
    for (int e = start; e < end; e += 8) {
        int   s[8];
        float cf[8];
        unsigned hv[8];
        #pragma unroll
        for (int j = 0; j < 8; ++j) {
            int ee = e + j;
            bool ok = ee < end;
            int es = ok ? ee : e;
            s[j]  = col[es];
            cf[j] = ok ? ex1[(size_t)es * 4 + head] : 0.f;
        }
        #pragma unroll
        for (int j = 0; j < 8; ++j)
            hv[j] = *(const unsigned*)(h1 + (size_t)s[j] * 128 + lane * 2);
        #pragma unroll
        for (int j = 0; j < 8; ++j) {
            float coef = cf[j] * rden;
            acc0 = fmaf(coef, __uint_as_float(hv[j] << 16), acc0);
            acc1 = fmaf(coef, __uint_as_float(hv[j] & 0xffff0000u), acc1);
        }
    }
    int c0 = lane * 2;
    float o0 = acc0 + b1[c0];
    float o1 = acc1 + b1[c0 + 1];
    o0 = o0 > 0.f ? o0 : expm1f(o0);
    o1 = o1 > 0.f ? o1 : expm1f(o1);
    unsigned ov = bf16rne(o0) | (bf16rne(o1) << 16);
    *(unsigned*)((char*)out1 + (size_t)wid * 256 + lane * 4) = ov;
}

// -------------------- GEMM2 (MFMA bf16): h2 = out1 @ W2, fused logits --------------------
__global__ __launch_bounds__(256) void k_gemm2(
    const unsigned short* __restrict__ in, const float* __restrict__ W,
    const float* __restrict__ attS, const float* __restrict__ attD,
    float* __restrict__ h2, float* __restrict__ as2, float* __restrict__ ad2, int N)
{
    __shared__ unsigned short Wt[16 * 128];    // [n][k] swizzled, 4 KB
    __shared__ unsigned short xs[64 * 128];    // [m][k] swizzled, 16 KB
    const int t = threadIdx.x;
    const int lane = t & 63;
    const int wv = t >> 6;
    const int ln = lane & 15;
    const int lg = lane >> 4;
    const int r0 = blockIdx.x * 64;

    #pragma unroll
    for (int j = 0; j < 8; ++j) {
        int idx = t * 8 + j;              // 2048 = 16 n x 128 k
        int n = idx & 15, k = idx >> 4;
        float v = W[(size_t)k * 16 + n];
        int byteo = n * 256 + ((k * 2) ^ ((n & 7) << 4));
        *(unsigned short*)((char*)Wt + byteo) = (unsigned short)bf16rne(v);
    }
    #pragma unroll
    for (int it = 0; it < 4; ++it) {
        int idx = t + it * 256;
        int m = idx >> 4, o = idx & 15;
        int rr = r0 + m;
        uint4 v = make_uint4(0, 0, 0, 0);
        if (rr < N) v = *(const uint4*)((const char*)(in + (size_t)rr * 128) + o * 16);
        int byteo = m * 256 + ((o * 16) ^ ((m & 7) << 4));
        *(uint4*)((char*)xs + byteo) = v;
    }
    __syncthreads();

    f32x4 acc = (f32x4)(0.f);
    #pragma unroll
    for (int kk = 0; kk < 4; ++kk) {
        int kb = (kk * 32 + lg * 8) * 2;
        int am = wv * 16 + ln;
        short8 a = *(const short8*)((char*)xs + am * 256 + (kb ^ ((am & 7) << 4)));
        short8 b = *(const short8*)((char*)Wt + ln * 256 + (kb ^ ((ln & 7) << 4)));
        acc = __builtin_amdgcn_mfma_f32_16x16x32_bf16(a, b, acc, 0, 0, 0);
    }

    float aSv = attS[ln], aDv = attD[ln];
    #pragma unroll
    for (int r = 0; r < 4; ++r) {
        int row = r0 + wv * 16 + lg * 4 + r;
        float s = acc[r] * aSv;
        float d = acc[r] * aDv;
        s += __shfl_xor(s, 1); s += __shfl_xor(s, 2); s += __shfl_xor(s, 4); s += __shfl_xor(s, 8);
        d += __shfl_xor(d, 1); d += __shfl_xor(d, 2); d += __shfl_xor(d, 4); d += __shfl_xor(d, 8);
        if (row < N) {
            h2[(size_t)row * 16 + ln] = acc[r];
            if (ln == 0) { as2[row] = s; ad2[row] = d; }
        }
    }
}

// -------------------- layer-2 edge coefficients --------------------
__global__ __launch_bounds__(256) void k_att2(
    const float* __restrict__ as2, const float* __restrict__ ad2,
    const int* __restrict__ rowptr, const int* __restrict__ col,
    float* __restrict__ ex2, float* __restrict__ rden2, int N)
{
    int wid = (int)(((unsigned)blockIdx.x * blockDim.x + threadIdx.x) >> 6);
    if (wid >= N) return;
    int lane = threadIdx.x & 63;
    int start = rowptr[wid], end = rowptr[wid + 1];
    float adv = ad2[wid];
    float den = 0.f;
    for (int e = start + lane; e < end; e += 64) {
        float ev = __expf(lrelu02(as2[col[e]] + adv));
        ex2[e] = ev;
        den += ev;
    }
    #pragma unroll
    for (int m = 32; m >= 1; m >>= 1) den += __shfl_xor(den, m);
    if (lane == 0) rden2[wid] = 1.f / den;
}

// -------------------- layer-2 aggregate --------------------
__global__ __launch_bounds__(256) void k_agg2(
    const float* __restrict__ h2, const float* __restrict__ ex2,
    const float* __restrict__ rden2, const int* __restrict__ rowptr,
    const int* __restrict__ col, const float* __restrict__ b2,
    float* __restrict__ out, int N)
{
    int wid = (int)(((unsigned)blockIdx.x * blockDim.x + threadIdx.x) >> 6);
    if (wid >= N) return;
    int lane = threadIdx.x & 63;
    int start = rowptr[wid], end = rowptr[wid + 1];
    float rden = rden2[wid];
    int sub = lane >> 4, c = lane & 15;
    float acc = 0.f;
    for (int e0 = start + sub; e0 < end; e0 += 16) {
        int   s[4];
        float cf[4];
        float hvv[4];
        #pragma unroll
        for (int j = 0; j < 4; ++j) {
            int ee = e0 + j * 4;
            bool ok = ee < end;
            int es = ok ? ee : e0;
            s[j]  = col[es];
            cf[j] = ok ? ex2[es] : 0.f;
        }
        #pragma unroll
        for (int j = 0; j < 4; ++j)
            hvv[j] = h2[(size_t)s[j] * 16 + c];
        #pragma unroll
        for (int j = 0; j < 4; ++j)
            acc = fmaf(cf[j] * rden, hvv[j], acc);
    }
    acc += __shfl_xor(acc, 16);
    acc += __shfl_xor(acc, 32);
    if (lane < 16) out[(size_t)wid * 16 + lane] = acc + b2[lane];
}

extern "C" void kernel_launch(void* const* d_in, const int* in_sizes, int n_in,
                              void* d_out, int out_size, void* d_ws, size_t ws_size,
                              hipStream_t stream)
{
    const float* x   = (const float*)d_in[0];
    const int*   ei  = (const int*)d_in[1];
    const float* W1  = (const float*)d_in[2];
    const float* aS1 = (const float*)d_in[3];
    const float* aD1 = (const float*)d_in[4];
    const float* b1  = (const float*)d_in[5];
    const float* W2  = (const float*)d_in[6];
    const float* aS2 = (const float*)d_in[7];
    const float* aD2 = (const float*)d_in[8];
    const float* b2  = (const float*)d_in[9];
    float* out = (float*)d_out;

    int N = in_sizes[0] / 128;
    int E = in_sizes[1] / 2;
    int ET = E + N;
    int nblk = (N + 2047) / 2048;

    char* w = (char*)d_ws;
    auto alloc = [&](size_t bytes) -> void* {
        void* p = (void*)w;
        w += (bytes + 255) & ~(size_t)255;
        return p;
    };
    unsigned short* h1   = (unsigned short*)alloc((size_t)N * 128 * 2);
    unsigned short* out1 = (unsigned short*)alloc((size_t)N * 128 * 2);
    float* as1   = (float*)alloc((size_t)N * 4 * 4);
    float* ad1   = (float*)alloc((size_t)N * 4 * 4);
    float* rden1 = (float*)alloc((size_t)N * 4 * 4);
    float* h2    = (float*)alloc((size_t)N * 16 * 4);
    float* as2v  = (float*)alloc((size_t)N * 4);
    float* ad2v  = (float*)alloc((size_t)N * 4);
    float* rden2 = (float*)alloc((size_t)N * 4);
    float* ex1   = (float*)alloc((size_t)ET * 4 * 4);
    float* ex2   = (float*)alloc((size_t)ET * 4);
    int* deg     = (int*)alloc((size_t)N * 4);
    int* rowptr  = (int*)alloc((size_t)(N + 1) * 4);
    int* rank    = (int*)alloc((size_t)ET * 4);
    int* col     = (int*)alloc((size_t)ET * 4);
    int* bsum    = (int*)alloc(64 * 4);

    hipMemsetAsync(deg, 0, (size_t)N * 4, stream);

    const int tb = 256;
    k_rank      <<<800, tb, 0, stream>>>(ei, deg, rank, E, N);
    k_scan_local<<<nblk, 256, 0, stream>>>(deg, rowptr, bsum, N);
    k_scan_bsum <<<1, 64, 0, stream>>>(bsum, nblk);
    k_scan_add  <<<nblk, 256, 0, stream>>>(rowptr, bsum, N, ET);
    k_fill2     <<<1024, tb, 0, stream>>>(ei, rank, rowptr, col, E, N);

    k_gemm1<<<(N + 63) / 64, 256, 0, stream>>>(x, W1, aS1, aD1, h1, as1, ad1, N);
    k_att1 <<<(N + 3) / 4, tb, 0, stream>>>(as1, ad1, rowptr, col, ex1, rden1, N);
    k_agg1 <<<(N + 3) / 4, tb, 0, stream>>>(h1, ex1, rden1, rowptr, col, b1, out1, N);
    k_gemm2<<<(N + 63) / 64, 256, 0, stream>>>(out1, W2, aS2, aD2, h2, as2v, ad2v, N);
    k_att2 <<<(N + 3) / 4, tb, 0, stream>>>(as2v, ad2v, rowptr, col, ex2, rden2, N);
    k_agg2 <<<(N + 3) / 4, tb, 0, stream>>>(h2, ex2, rden2, rowptr, col, b2, out, N);
}

// Round 7
// 182.638 us; speedup vs baseline: 2.1660x; 1.0202x over previous
//
#include <hip/hip_runtime.h>

typedef __attribute__((ext_vector_type(8))) short short8;
typedef __attribute__((ext_vector_type(4))) float f32x4;

__device__ __forceinline__ float lrelu02(float a) { return a > 0.0f ? a : 0.2f * a; }

__device__ __forceinline__ unsigned bf16rne(float f) {
    unsigned u = __float_as_uint(f);
    return (u + 0x7fffu + ((u >> 16) & 1u)) >> 16;
}

// -------------------- zero deg (hipMemsetAsync's fill kernel was 41 us!) --------------------
__global__ __launch_bounds__(256) void k_zero(int4* __restrict__ p, int n4) {
    int i = blockIdx.x * blockDim.x + threadIdx.x;
    if (i < n4) p[i] = make_int4(0, 0, 0, 0);
}

// -------------------- fused: CSR rank pass (atomics) || GEMM1 (MFMA bf16) ----------------
// blocks [0, RB): rank; blocks [RB, RB+G1): gemm1. Independent work, overlapped on-device.
__global__ __launch_bounds__(256) void k_g1rank(
    const float* __restrict__ x, const float* __restrict__ W,
    const float* __restrict__ attS, const float* __restrict__ attD,
    unsigned short* __restrict__ h1, float* __restrict__ as1, float* __restrict__ ad1,
    const int* __restrict__ ei, int* __restrict__ deg, int* __restrict__ rank,
    int E, int N, int RB)
{
    __shared__ unsigned short Wt[128 * 128];   // [n][k], 32 KB, swizzled
    __shared__ unsigned short xs[64 * 128];    // [m][k], 16 KB, swizzled (reused for out)

    if (blockIdx.x < RB) {
        // ---- rank path: one returning atomic per edge ----
        int tid = blockIdx.x * blockDim.x + threadIdx.x;
        int nthr = RB * blockDim.x;
        int E4 = E & ~3;
        for (int b = tid * 4; b < E4; b += nthr * 4) {
            int4 d = *(const int4*)(ei + E + b);
            int4 r;
            r.x = atomicAdd(&deg[d.x], 1);
            r.y = atomicAdd(&deg[d.y], 1);
            r.z = atomicAdd(&deg[d.z], 1);
            r.w = atomicAdd(&deg[d.w], 1);
            *(int4*)(rank + b) = r;
        }
        for (int e = E4 + tid; e < E; e += nthr)
            rank[e] = atomicAdd(&deg[ei[E + e]], 1);
        for (int i = tid; i < N; i += nthr)
            rank[E + i] = atomicAdd(&deg[i], 1);        // self loops
        return;
    }

    // ---- gemm1 path ----
    const int t = threadIdx.x;
    const int lane = t & 63;
    const int wv = t >> 6;
    const int ln = lane & 15;
    const int lg = lane >> 4;
    const int r0 = (blockIdx.x - RB) * 64;

    {
        int kbase = t >> 5, n0 = (t & 31) * 4;
        for (int it = 0; it < 16; ++it) {
            int k = kbase + it * 8;
            float4 v = *(const float4*)&W[(size_t)k * 128 + n0];
            float vv[4] = {v.x, v.y, v.z, v.w};
            #pragma unroll
            for (int j = 0; j < 4; ++j) {
                int n = n0 + j;
                int byteo = n * 256 + ((k * 2) ^ ((n & 7) << 4));
                *(unsigned short*)((char*)Wt + byteo) = (unsigned short)bf16rne(vv[j]);
            }
        }
    }
    {
        int mbase = t >> 5, k0 = (t & 31) * 4;
        for (int it = 0; it < 8; ++it) {
            int m = mbase + it * 8;
            int rr = r0 + m;
            float4 v = make_float4(0.f, 0.f, 0.f, 0.f);
            if (rr < N) v = *(const float4*)&x[(size_t)rr * 128 + k0];
            unsigned lo = bf16rne(v.x) | (bf16rne(v.y) << 16);
            unsigned hi = bf16rne(v.z) | (bf16rne(v.w) << 16);
            int byteo = m * 256 + ((k0 * 2) ^ ((m & 7) << 4));
            *(uint2*)((char*)xs + byteo) = make_uint2(lo, hi);
        }
    }
    __syncthreads();

    f32x4 acc[8];
    #pragma unroll
    for (int i = 0; i < 8; ++i) acc[i] = (f32x4)(0.f);

    #pragma unroll
    for (int kk = 0; kk < 4; ++kk) {
        int kb = (kk * 32 + lg * 8) * 2;
        int am = wv * 16 + ln;
        short8 a = *(const short8*)((char*)xs + am * 256 + (kb ^ ((am & 7) << 4)));
        #pragma unroll
        for (int tile = 0; tile < 8; ++tile) {
            int n = tile * 16 + ln;
            short8 b = *(const short8*)((char*)Wt + n * 256 + (kb ^ ((n & 7) << 4)));
            acc[tile] = __builtin_amdgcn_mfma_f32_16x16x32_bf16(a, b, acc[tile], 0, 0, 0);
        }
    }

    float aSt[8], aDt[8];
    #pragma unroll
    for (int tile = 0; tile < 8; ++tile) {
        aSt[tile] = attS[tile * 16 + ln];
        aDt[tile] = attD[tile * 16 + ln];
    }
    #pragma unroll
    for (int r = 0; r < 4; ++r) {
        int row = r0 + wv * 16 + lg * 4 + r;
        #pragma unroll
        for (int h = 0; h < 4; ++h) {
            float s = acc[2*h][r] * aSt[2*h] + acc[2*h+1][r] * aSt[2*h+1];
            float d = acc[2*h][r] * aDt[2*h] + acc[2*h+1][r] * aDt[2*h+1];
            s += __shfl_xor(s, 1); s += __shfl_xor(s, 2); s += __shfl_xor(s, 4); s += __shfl_xor(s, 8);
            d += __shfl_xor(d, 1); d += __shfl_xor(d, 2); d += __shfl_xor(d, 4); d += __shfl_xor(d, 8);
            if (ln == h * 4 + r && row < N) {
                as1[row * 4 + h] = s;
                ad1[row * 4 + h] = d;
            }
        }
    }

    __syncthreads();
    #pragma unroll
    for (int tile = 0; tile < 8; ++tile) {
        #pragma unroll
        for (int r = 0; r < 4; ++r) {
            int m = wv * 16 + lg * 4 + r;
            xs[m * 128 + tile * 16 + ln] = (unsigned short)bf16rne(acc[tile][r]);
        }
    }
    __syncthreads();
    #pragma unroll
    for (int it = 0; it < 4; ++it) {
        int idx = t + it * 256;
        int m = idx >> 4, o = idx & 15;
        if (r0 + m < N)
            *(uint4*)((char*)(h1 + (size_t)(r0 + m) * 128) + o * 16) =
                *(const uint4*)((const char*)(xs + m * 128) + o * 16);
    }
}

// 3-phase hierarchical exclusive scan over deg[N] -> rowptr[N+1]
__global__ __launch_bounds__(256) void k_scan_local(
    const int* __restrict__ deg, int* __restrict__ rowptr, int* __restrict__ bsum, int N)
{
    const int t = threadIdx.x;
    const int base = blockIdx.x * 2048 + t * 8;
    int v[8];
    int s = 0;
    #pragma unroll
    for (int j = 0; j < 8; ++j) {
        int idx = base + j;
        v[j] = (idx < N) ? deg[idx] : 0;
        s += v[j];
    }
    __shared__ int ts[256];
    ts[t] = s;
    __syncthreads();
    #pragma unroll
    for (int off = 1; off < 256; off <<= 1) {
        int u = (t >= off) ? ts[t - off] : 0;
        __syncthreads();
        ts[t] += u;
        __syncthreads();
    }
    int ex = (t == 0) ? 0 : ts[t - 1];
    #pragma unroll
    for (int j = 0; j < 8; ++j) {
        int idx = base + j;
        if (idx < N) rowptr[idx] = ex;
        ex += v[j];
    }
    if (t == 255) bsum[blockIdx.x] = ts[255];
}

__global__ void k_scan_bsum(int* __restrict__ bsum, int nblk) {
    int t = threadIdx.x;
    int v = (t < nblk) ? bsum[t] : 0;
    int inc = v;
    #pragma unroll
    for (int off = 1; off < 64; off <<= 1) {
        int u = __shfl_up(inc, off);
        if (t >= off) inc += u;
    }
    if (t < nblk) bsum[t] = inc - v;
}

__global__ __launch_bounds__(256) void k_scan_add(
    int* __restrict__ rowptr, const int* __restrict__ bsum, int N, int ET)
{
    const int t = threadIdx.x;
    const int base = blockIdx.x * 2048 + t * 8;
    int off = bsum[blockIdx.x];
    #pragma unroll
    for (int j = 0; j < 8; ++j) {
        int idx = base + j;
        if (idx < N) rowptr[idx] += off;
    }
    if (blockIdx.x == 0 && t == 0) rowptr[N] = ET;
}

// -------------------- CSR fill: atomic-free gather/scatter --------------------
__global__ __launch_bounds__(256) void k_fill2(const int* __restrict__ ei,
                                               const int* __restrict__ rank,
                                               const int* __restrict__ rowptr,
                                               int* __restrict__ col, int E, int N) {
    int tid = blockIdx.x * blockDim.x + threadIdx.x;
    int nthr = gridDim.x * blockDim.x;
    int E4 = E & ~3;
    for (int b = tid * 4; b < E4; b += nthr * 4) {
        int4 d = *(const int4*)(ei + E + b);
        int4 s = *(const int4*)(ei + b);
        int4 r = *(const int4*)(rank + b);
        col[rowptr[d.x] + r.x] = s.x;
        col[rowptr[d.y] + r.y] = s.y;
        col[rowptr[d.z] + r.z] = s.z;
        col[rowptr[d.w] + r.w] = s.w;
    }
    for (int e = E4 + tid; e < E; e += nthr)
        col[rowptr[ei[E + e]] + rank[e]] = ei[e];
    for (int i = tid; i < N; i += nthr)
        col[rowptr[i] + rank[E + i]] = i;               // self loops
}

// -------------------- layer-1 edge coefficients (one wave per dst node) --------------------
__global__ __launch_bounds__(256) void k_att1(
    const float* __restrict__ as1, const float* __restrict__ ad1,
    const int* __restrict__ rowptr, const int* __restrict__ col,
    float* __restrict__ ex1, float* __restrict__ rden1, int N)
{
    int wid = (int)(((unsigned)blockIdx.x * blockDim.x + threadIdx.x) >> 6);
    if (wid >= N) return;
    int lane = threadIdx.x & 63;
    int start = rowptr[wid], end = rowptr[wid + 1];
    const float4 ad = *(const float4*)(ad1 + (size_t)wid * 4);

    float den0 = 0.f, den1 = 0.f, den2 = 0.f, den3 = 0.f;
    for (int e = start + lane; e < end; e += 64) {
        int src = col[e];
        const float4 a = *(const float4*)(as1 + (size_t)src * 4);
        float e0 = __expf(lrelu02(a.x + ad.x));
        float e1 = __expf(lrelu02(a.y + ad.y));
        float e2 = __expf(lrelu02(a.z + ad.z));
        float e3 = __expf(lrelu02(a.w + ad.w));
        *(float4*)(ex1 + (size_t)e * 4) = make_float4(e0, e1, e2, e3);
        den0 += e0; den1 += e1; den2 += e2; den3 += e3;
    }
    #pragma unroll
    for (int m = 32; m >= 1; m >>= 1) {
        den0 += __shfl_xor(den0, m); den1 += __shfl_xor(den1, m);
        den2 += __shfl_xor(den2, m); den3 += __shfl_xor(den3, m);
    }
    if (lane == 0)
        *(float4*)(rden1 + (size_t)wid * 4) =
            make_float4(1.f / den0, 1.f / den1, 1.f / den2, 1.f / den3);
}

// -------------------- layer-1 aggregate: one wave per dst, 8 gathers in flight; bf16 out --
__global__ __launch_bounds__(256) void k_agg1(
    const unsigned short* __restrict__ h1, const float* __restrict__ ex1,
    const float* __restrict__ rden1, const int* __restrict__ rowptr,
    const int* __restrict__ col, const float* __restrict__ b1,
    unsigned short* __restrict__ out1, int N)
{
    int wid = (int)(((unsigned)blockIdx.x * blockDim.x + threadIdx.x) >> 6);
    if (wid >= N) return;
    int lane = threadIdx.x & 63;
    int head = lane >> 4;
    float rden = rden1[wid * 4 + head];
    int start = rowptr[wid], end = rowptr[wid + 1];

    float acc0 = 0.f, acc1 = 0.f;
    for (int e = start; e < end; e += 8) {
        int   s[8];
        float cf[8];
        unsigned hv[8];
        #pragma unroll
        for (int j = 0; j < 8; ++j) {
            int ee = e + j;
            bool ok = ee < end;
            int es = ok ? ee : e;
            s[j]  = col[es];
            cf[j] = ok ? ex1[(size_t)es * 4 + head] : 0.f;
        }
        #pragma unroll
        for (int j = 0; j < 8; ++j)
            hv[j] = *(const unsigned*)(h1 + (size_t)s[j] * 128 + lane * 2);
        #pragma unroll
        for (int j = 0; j < 8; ++j) {
            float coef = cf[j] * rden;
            acc0 = fmaf(coef, __uint_as_float(hv[j] << 16), acc0);
            acc1 = fmaf(coef, __uint_as_float(hv[j] & 0xffff0000u), acc1);
        }
    }
    int c0 = lane * 2;
    float o0 = acc0 + b1[c0];
    float o1 = acc1 + b1[c0 + 1];
    o0 = o0 > 0.f ? o0 : expm1f(o0);
    o1 = o1 > 0.f ? o1 : expm1f(o1);
    unsigned ov = bf16rne(o0) | (bf16rne(o1) << 16);
    *(unsigned*)((char*)out1 + (size_t)wid * 256 + lane * 4) = ov;
}

// -------------------- GEMM2 (MFMA bf16): h2 = out1 @ W2, fused logits --------------------
__global__ __launch_bounds__(256) void k_gemm2(
    const unsigned short* __restrict__ in, const float* __restrict__ W,
    const float* __restrict__ attS, const float* __restrict__ attD,
    float* __restrict__ h2, float* __restrict__ as2, float* __restrict__ ad2, int N)
{
    __shared__ unsigned short Wt[16 * 128];    // [n][k] swizzled, 4 KB
    __shared__ unsigned short xs[64 * 128];    // [m][k] swizzled, 16 KB
    const int t = threadIdx.x;
    const int lane = t & 63;
    const int wv = t >> 6;
    const int ln = lane & 15;
    const int lg = lane >> 4;
    const int r0 = blockIdx.x * 64;

    #pragma unroll
    for (int j = 0; j < 8; ++j) {
        int idx = t * 8 + j;
        int n = idx & 15, k = idx >> 4;
        float v = W[(size_t)k * 16 + n];
        int byteo = n * 256 + ((k * 2) ^ ((n & 7) << 4));
        *(unsigned short*)((char*)Wt + byteo) = (unsigned short)bf16rne(v);
    }
    #pragma unroll
    for (int it = 0; it < 4; ++it) {
        int idx = t + it * 256;
        int m = idx >> 4, o = idx & 15;
        int rr = r0 + m;
        uint4 v = make_uint4(0, 0, 0, 0);
        if (rr < N) v = *(const uint4*)((const char*)(in + (size_t)rr * 128) + o * 16);
        int byteo = m * 256 + ((o * 16) ^ ((m & 7) << 4));
        *(uint4*)((char*)xs + byteo) = v;
    }
    __syncthreads();

    f32x4 acc = (f32x4)(0.f);
    #pragma unroll
    for (int kk = 0; kk < 4; ++kk) {
        int kb = (kk * 32 + lg * 8) * 2;
        int am = wv * 16 + ln;
        short8 a = *(const short8*)((char*)xs + am * 256 + (kb ^ ((am & 7) << 4)));
        short8 b = *(const short8*)((char*)Wt + ln * 256 + (kb ^ ((ln & 7) << 4)));
        acc = __builtin_amdgcn_mfma_f32_16x16x32_bf16(a, b, acc, 0, 0, 0);
    }

    float aSv = attS[ln], aDv = attD[ln];
    #pragma unroll
    for (int r = 0; r < 4; ++r) {
        int row = r0 + wv * 16 + lg * 4 + r;
        float s = acc[r] * aSv;
        float d = acc[r] * aDv;
        s += __shfl_xor(s, 1); s += __shfl_xor(s, 2); s += __shfl_xor(s, 4); s += __shfl_xor(s, 8);
        d += __shfl_xor(d, 1); d += __shfl_xor(d, 2); d += __shfl_xor(d, 4); d += __shfl_xor(d, 8);
        if (row < N) {
            h2[(size_t)row * 16 + ln] = acc[r];
            if (ln == 0) { as2[row] = s; ad2[row] = d; }
        }
    }
}

// -------------------- layer-2 edge coefficients --------------------
__global__ __launch_bounds__(256) void k_att2(
    const float* __restrict__ as2, const float* __restrict__ ad2,
    const int* __restrict__ rowptr, const int* __restrict__ col,
    float* __restrict__ ex2, float* __restrict__ rden2, int N)
{
    int wid = (int)(((unsigned)blockIdx.x * blockDim.x + threadIdx.x) >> 6);
    if (wid >= N) return;
    int lane = threadIdx.x & 63;
    int start = rowptr[wid], end = rowptr[wid + 1];
    float adv = ad2[wid];
    float den = 0.f;
    for (int e = start + lane; e < end; e += 64) {
        float ev = __expf(lrelu02(as2[col[e]] + adv));
        ex2[e] = ev;
        den += ev;
    }
    #pragma unroll
    for (int m = 32; m >= 1; m >>= 1) den += __shfl_xor(den, m);
    if (lane == 0) rden2[wid] = 1.f / den;
}

// -------------------- layer-2 aggregate --------------------
__global__ __launch_bounds__(256) void k_agg2(
    const float* __restrict__ h2, const float* __restrict__ ex2,
    const float* __restrict__ rden2, const int* __restrict__ rowptr,
    const int* __restrict__ col, const float* __restrict__ b2,
    float* __restrict__ out, int N)
{
    int wid = (int)(((unsigned)blockIdx.x * blockDim.x + threadIdx.x) >> 6);
    if (wid >= N) return;
    int lane = threadIdx.x & 63;
    int start = rowptr[wid], end = rowptr[wid + 1];
    float rden = rden2[wid];
    int sub = lane >> 4, c = lane & 15;
    float acc = 0.f;
    for (int e0 = start + sub; e0 < end; e0 += 16) {
        int   s[4];
        float cf[4];
        float hvv[4];
        #pragma unroll
        for (int j = 0; j < 4; ++j) {
            int ee = e0 + j * 4;
            bool ok = ee < end;
            int es = ok ? ee : e0;
            s[j]  = col[es];
            cf[j] = ok ? ex2[es] : 0.f;
        }
        #pragma unroll
        for (int j = 0; j < 4; ++j)
            hvv[j] = h2[(size_t)s[j] * 16 + c];
        #pragma unroll
        for (int j = 0; j < 4; ++j)
            acc = fmaf(cf[j] * rden, hvv[j], acc);
    }
    acc += __shfl_xor(acc, 16);
    acc += __shfl_xor(acc, 32);
    if (lane < 16) out[(size_t)wid * 16 + lane] = acc + b2[lane];
}

extern "C" void kernel_launch(void* const* d_in, const int* in_sizes, int n_in,
                              void* d_out, int out_size, void* d_ws, size_t ws_size,
                              hipStream_t stream)
{
    const float* x   = (const float*)d_in[0];
    const int*   ei  = (const int*)d_in[1];
    const float* W1  = (const float*)d_in[2];
    const float* aS1 = (const float*)d_in[3];
    const float* aD1 = (const float*)d_in[4];
    const float* b1  = (const float*)d_in[5];
    const float* W2  = (const float*)d_in[6];
    const float* aS2 = (const float*)d_in[7];
    const float* aD2 = (const float*)d_in[8];
    const float* b2  = (const float*)d_in[9];
    float* out = (float*)d_out;

    int N = in_sizes[0] / 128;
    int E = in_sizes[1] / 2;
    int ET = E + N;
    int nblk = (N + 2047) / 2048;
    int G1 = (N + 63) / 64;
    const int RB = 800;

    char* w = (char*)d_ws;
    auto alloc = [&](size_t bytes) -> void* {
        void* p = (void*)w;
        w += (bytes + 255) & ~(size_t)255;
        return p;
    };
    unsigned short* h1   = (unsigned short*)alloc((size_t)N * 128 * 2);
    unsigned short* out1 = (unsigned short*)alloc((size_t)N * 128 * 2);
    float* as1   = (float*)alloc((size_t)N * 4 * 4);
    float* ad1   = (float*)alloc((size_t)N * 4 * 4);
    float* rden1 = (float*)alloc((size_t)N * 4 * 4);
    float* h2    = (float*)alloc((size_t)N * 16 * 4);
    float* as2v  = (float*)alloc((size_t)N * 4);
    float* ad2v  = (float*)alloc((size_t)N * 4);
    float* rden2 = (float*)alloc((size_t)N * 4);
    float* ex1   = (float*)alloc((size_t)ET * 4 * 4);
    float* ex2   = (float*)alloc((size_t)ET * 4);
    int* deg     = (int*)alloc((size_t)N * 4);
    int* rowptr  = (int*)alloc((size_t)(N + 1) * 4);
    int* rank    = (int*)alloc((size_t)ET * 4);
    int* col     = (int*)alloc((size_t)ET * 4);
    int* bsum    = (int*)alloc(64 * 4);

    const int tb = 256;
    int n4 = (N + 3) / 4;
    k_zero  <<<(n4 + tb - 1) / tb, tb, 0, stream>>>((int4*)deg, n4);
    k_g1rank<<<RB + G1, tb, 0, stream>>>(x, W1, aS1, aD1, h1, as1, ad1,
                                         ei, deg, rank, E, N, RB);
    k_scan_local<<<nblk, 256, 0, stream>>>(deg, rowptr, bsum, N);
    k_scan_bsum <<<1, 64, 0, stream>>>(bsum, nblk);
    k_scan_add  <<<nblk, 256, 0, stream>>>(rowptr, bsum, N, ET);
    k_fill2     <<<1024, tb, 0, stream>>>(ei, rank, rowptr, col, E, N);

    k_att1 <<<(N + 3) / 4, tb, 0, stream>>>(as1, ad1, rowptr, col, ex1, rden1, N);
    k_agg1 <<<(N + 3) / 4, tb, 0, stream>>>(h1, ex1, rden1, rowptr, col, b1, out1, N);
    k_gemm2<<<(N + 63) / 64, tb, 0, stream>>>(out1, W2, aS2, aD2, h2, as2v, ad2v, N);
    k_att2 <<<(N + 3) / 4, tb, 0, stream>>>(as2v, ad2v, rowptr, col, ex2, rden2, N);
    k_agg2 <<<(N + 3) / 4, tb, 0, stream>>>(h2, ex2, rden2, rowptr, col, b2, out, N);
}

// Round 8
// 164.259 us; speedup vs baseline: 2.4083x; 1.1119x over previous
//
#include <hip/hip_runtime.h>

typedef __attribute__((ext_vector_type(8))) short short8;
typedef __attribute__((ext_vector_type(4))) float f32x4;

__device__ __forceinline__ float lrelu02(float a) { return a > 0.0f ? a : 0.2f * a; }

__device__ __forceinline__ unsigned bf16rne(float f) {
    unsigned u = __float_as_uint(f);
    return (u + 0x7fffu + ((u >> 16) & 1u)) >> 16;
}

// -------------------- zero deg --------------------
__global__ __launch_bounds__(256) void k_zero(int4* __restrict__ p, int n4) {
    int i = blockIdx.x * blockDim.x + threadIdx.x;
    if (i < n4) p[i] = make_int4(0, 0, 0, 0);
}

// -------------------- fused: CSR rank pass (atomics) || GEMM1 (MFMA bf16) ----------------
__global__ __launch_bounds__(256) void k_g1rank(
    const float* __restrict__ x, const float* __restrict__ W,
    const float* __restrict__ attS, const float* __restrict__ attD,
    unsigned short* __restrict__ h1, float* __restrict__ as1, float* __restrict__ ad1,
    const int* __restrict__ ei, int* __restrict__ deg, int* __restrict__ rank,
    int E, int N, int RB)
{
    __shared__ unsigned short Wt[128 * 128];   // [n][k], 32 KB, swizzled
    __shared__ unsigned short xs[64 * 128];    // [m][k], 16 KB, swizzled (reused for out)

    if (blockIdx.x < RB) {
        // ---- rank path ----
        int tid = blockIdx.x * blockDim.x + threadIdx.x;
        int nthr = RB * blockDim.x;
        int E4 = E & ~3;
        for (int b = tid * 4; b < E4; b += nthr * 4) {
            int4 d = *(const int4*)(ei + E + b);
            int4 r;
            r.x = atomicAdd(&deg[d.x], 1);
            r.y = atomicAdd(&deg[d.y], 1);
            r.z = atomicAdd(&deg[d.z], 1);
            r.w = atomicAdd(&deg[d.w], 1);
            *(int4*)(rank + b) = r;
        }
        for (int e = E4 + tid; e < E; e += nthr)
            rank[e] = atomicAdd(&deg[ei[E + e]], 1);
        for (int i = tid; i < N; i += nthr)
            rank[E + i] = atomicAdd(&deg[i], 1);        // self loops
        return;
    }

    // ---- gemm1 path ----
    const int t = threadIdx.x;
    const int lane = t & 63;
    const int wv = t >> 6;
    const int ln = lane & 15;
    const int lg = lane >> 4;
    const int r0 = (blockIdx.x - RB) * 64;

    // stage W^T: per thread, 4 k-consecutive values of one n packed into a uint2 write
    #pragma unroll
    for (int i = 0; i < 16; ++i) {
        int flat = i * 256 + t;
        int n = flat & 127;
        int k0 = (flat >> 7) * 4;
        float v0 = W[(size_t)(k0 + 0) * 128 + n];
        float v1 = W[(size_t)(k0 + 1) * 128 + n];
        float v2 = W[(size_t)(k0 + 2) * 128 + n];
        float v3 = W[(size_t)(k0 + 3) * 128 + n];
        uint2 pk;
        pk.x = bf16rne(v0) | (bf16rne(v1) << 16);
        pk.y = bf16rne(v2) | (bf16rne(v3) << 16);
        int byteo = n * 256 + ((k0 * 2) ^ ((n & 7) << 4));
        *(uint2*)((char*)Wt + byteo) = pk;
    }
    // stage x tile (k-contiguous per thread already -> conflict-light)
    {
        int mbase = t >> 5, k0 = (t & 31) * 4;
        #pragma unroll
        for (int it = 0; it < 8; ++it) {
            int m = mbase + it * 8;
            int rr = r0 + m;
            float4 v = make_float4(0.f, 0.f, 0.f, 0.f);
            if (rr < N) v = *(const float4*)&x[(size_t)rr * 128 + k0];
            unsigned lo = bf16rne(v.x) | (bf16rne(v.y) << 16);
            unsigned hi = bf16rne(v.z) | (bf16rne(v.w) << 16);
            int byteo = m * 256 + ((k0 * 2) ^ ((m & 7) << 4));
            *(uint2*)((char*)xs + byteo) = make_uint2(lo, hi);
        }
    }
    __syncthreads();

    f32x4 acc[8];
    #pragma unroll
    for (int i = 0; i < 8; ++i) acc[i] = (f32x4)(0.f);

    #pragma unroll
    for (int kk = 0; kk < 4; ++kk) {
        int kb = (kk * 32 + lg * 8) * 2;
        int am = wv * 16 + ln;
        short8 a = *(const short8*)((char*)xs + am * 256 + (kb ^ ((am & 7) << 4)));
        #pragma unroll
        for (int tile = 0; tile < 8; ++tile) {
            int n = tile * 16 + ln;
            short8 b = *(const short8*)((char*)Wt + n * 256 + (kb ^ ((n & 7) << 4)));
            acc[tile] = __builtin_amdgcn_mfma_f32_16x16x32_bf16(a, b, acc[tile], 0, 0, 0);
        }
    }

    float aSt[8], aDt[8];
    #pragma unroll
    for (int tile = 0; tile < 8; ++tile) {
        aSt[tile] = attS[tile * 16 + ln];
        aDt[tile] = attD[tile * 16 + ln];
    }
    #pragma unroll
    for (int r = 0; r < 4; ++r) {
        int row = r0 + wv * 16 + lg * 4 + r;
        #pragma unroll
        for (int h = 0; h < 4; ++h) {
            float s = acc[2*h][r] * aSt[2*h] + acc[2*h+1][r] * aSt[2*h+1];
            float d = acc[2*h][r] * aDt[2*h] + acc[2*h+1][r] * aDt[2*h+1];
            s += __shfl_xor(s, 1); s += __shfl_xor(s, 2); s += __shfl_xor(s, 4); s += __shfl_xor(s, 8);
            d += __shfl_xor(d, 1); d += __shfl_xor(d, 2); d += __shfl_xor(d, 4); d += __shfl_xor(d, 8);
            if (ln == h * 4 + r && row < N) {
                as1[row * 4 + h] = s;
                ad1[row * 4 + h] = d;
            }
        }
    }

    // h1 write-out via swizzled LDS staging (conflict-light both sides)
    __syncthreads();
    #pragma unroll
    for (int tile = 0; tile < 8; ++tile) {
        #pragma unroll
        for (int r = 0; r < 4; ++r) {
            int m = wv * 16 + lg * 4 + r;
            int byteo = m * 256 + (((tile * 16 + ln) * 2) ^ ((m & 7) << 4));
            *(unsigned short*)((char*)xs + byteo) = (unsigned short)bf16rne(acc[tile][r]);
        }
    }
    __syncthreads();
    #pragma unroll
    for (int it = 0; it < 4; ++it) {
        int idx = t + it * 256;
        int m = idx >> 4, o = idx & 15;
        int byteo = m * 256 + ((o * 16) ^ ((m & 7) << 4));
        if (r0 + m < N)
            *(uint4*)((char*)(h1 + (size_t)(r0 + m) * 128) + o * 16) =
                *(const uint4*)((const char*)xs + byteo);
    }
}

// -------------------- hierarchical scan (2 kernels) --------------------
__global__ __launch_bounds__(256) void k_scan_local(
    const int* __restrict__ deg, int* __restrict__ rowptr, int* __restrict__ bsum, int N)
{
    const int t = threadIdx.x;
    const int base = blockIdx.x * 2048 + t * 8;
    int v[8];
    int s = 0;
    #pragma unroll
    for (int j = 0; j < 8; ++j) {
        int idx = base + j;
        v[j] = (idx < N) ? deg[idx] : 0;
        s += v[j];
    }
    __shared__ int ts[256];
    ts[t] = s;
    __syncthreads();
    #pragma unroll
    for (int off = 1; off < 256; off <<= 1) {
        int u = (t >= off) ? ts[t - off] : 0;
        __syncthreads();
        ts[t] += u;
        __syncthreads();
    }
    int ex = (t == 0) ? 0 : ts[t - 1];
    #pragma unroll
    for (int j = 0; j < 8; ++j) {
        int idx = base + j;
        if (idx < N) rowptr[idx] = ex;
        ex += v[j];
    }
    if (t == 255) bsum[blockIdx.x] = ts[255];
}

__global__ __launch_bounds__(256) void k_scan_add(
    int* __restrict__ rowptr, const int* __restrict__ bsum, int N, int ET)
{
    const int t = threadIdx.x;
    __shared__ int soff;
    if (t < 64) {
        int v = (t < (int)blockIdx.x) ? bsum[t] : 0;    // nblk <= 64
        #pragma unroll
        for (int m = 32; m >= 1; m >>= 1) v += __shfl_xor(v, m);
        if (t == 0) soff = v;
    }
    __syncthreads();
    int off = soff;
    const int base = blockIdx.x * 2048 + t * 8;
    #pragma unroll
    for (int j = 0; j < 8; ++j) {
        int idx = base + j;
        if (idx < N) rowptr[idx] += off;
    }
    if (blockIdx.x == 0 && t == 0) rowptr[N] = ET;
}

// -------------------- CSR fill: atomic-free --------------------
__global__ __launch_bounds__(256) void k_fill2(const int* __restrict__ ei,
                                               const int* __restrict__ rank,
                                               const int* __restrict__ rowptr,
                                               int* __restrict__ col, int E, int N) {
    int tid = blockIdx.x * blockDim.x + threadIdx.x;
    int nthr = gridDim.x * blockDim.x;
    int E4 = E & ~3;
    for (int b = tid * 4; b < E4; b += nthr * 4) {
        int4 d = *(const int4*)(ei + E + b);
        int4 s = *(const int4*)(ei + b);
        int4 r = *(const int4*)(rank + b);
        col[rowptr[d.x] + r.x] = s.x;
        col[rowptr[d.y] + r.y] = s.y;
        col[rowptr[d.z] + r.z] = s.z;
        col[rowptr[d.w] + r.w] = s.w;
    }
    for (int e = E4 + tid; e < E; e += nthr)
        col[rowptr[ei[E + e]] + rank[e]] = ei[e];
    for (int i = tid; i < N; i += nthr)
        col[rowptr[i] + rank[E + i]] = i;
}

// ---------- layer-1 fused softmax+aggregate (recompute exp, no ex1 buffer) ----------
__global__ __launch_bounds__(256) void k_agg1(
    const unsigned short* __restrict__ h1, const float* __restrict__ as1,
    const float* __restrict__ ad1, const int* __restrict__ rowptr,
    const int* __restrict__ col, const float* __restrict__ b1,
    unsigned short* __restrict__ out1, int N)
{
    int wid = (int)(((unsigned)blockIdx.x * blockDim.x + threadIdx.x) >> 6);
    if (wid >= N) return;
    int lane = threadIdx.x & 63;
    int start = rowptr[wid], end = rowptr[wid + 1];
    const float4 ad = *(const float4*)(ad1 + (size_t)wid * 4);

    // pass 1: denominators
    float den0 = 0.f, den1 = 0.f, den2 = 0.f, den3 = 0.f;
    for (int e = start + lane; e < end; e += 64) {
        int src = col[e];
        const float4 a = *(const float4*)(as1 + (size_t)src * 4);
        den0 += __expf(lrelu02(a.x + ad.x));
        den1 += __expf(lrelu02(a.y + ad.y));
        den2 += __expf(lrelu02(a.z + ad.z));
        den3 += __expf(lrelu02(a.w + ad.w));
    }
    #pragma unroll
    for (int m = 32; m >= 1; m >>= 1) {
        den0 += __shfl_xor(den0, m); den1 += __shfl_xor(den1, m);
        den2 += __shfl_xor(den2, m); den3 += __shfl_xor(den3, m);
    }
    int head = lane >> 4;
    float rden = head == 0 ? 1.f/den0 : head == 1 ? 1.f/den1 : head == 2 ? 1.f/den2 : 1.f/den3;
    float adh  = head == 0 ? ad.x : head == 1 ? ad.y : head == 2 ? ad.z : ad.w;

    // pass 2: weighted gather, 8 edges in flight, recompute exp (as1 L1-hot)
    float acc0 = 0.f, acc1 = 0.f;
    for (int e = start; e < end; e += 8) {
        int s[8];
        float av[8], km[8];
        unsigned hv[8];
        #pragma unroll
        for (int j = 0; j < 8; ++j) {
            int ee = e + j;
            bool ok = ee < end;
            int es = ok ? ee : e;
            s[j]  = col[es];
            km[j] = ok ? 1.f : 0.f;
        }
        #pragma unroll
        for (int j = 0; j < 8; ++j)
            av[j] = as1[(size_t)s[j] * 4 + head];
        #pragma unroll
        for (int j = 0; j < 8; ++j)
            hv[j] = *(const unsigned*)(h1 + (size_t)s[j] * 128 + lane * 2);
        #pragma unroll
        for (int j = 0; j < 8; ++j) {
            float coef = km[j] * __expf(lrelu02(av[j] + adh)) * rden;
            acc0 = fmaf(coef, __uint_as_float(hv[j] << 16), acc0);
            acc1 = fmaf(coef, __uint_as_float(hv[j] & 0xffff0000u), acc1);
        }
    }
    int c0 = lane * 2;
    float o0 = acc0 + b1[c0];
    float o1 = acc1 + b1[c0 + 1];
    o0 = o0 > 0.f ? o0 : expm1f(o0);
    o1 = o1 > 0.f ? o1 : expm1f(o1);
    unsigned ov = bf16rne(o0) | (bf16rne(o1) << 16);
    *(unsigned*)((char*)out1 + (size_t)wid * 256 + lane * 4) = ov;
}

// -------------------- GEMM2 (MFMA bf16): h2 = out1 @ W2, fused logits --------------------
__global__ __launch_bounds__(256) void k_gemm2(
    const unsigned short* __restrict__ in, const float* __restrict__ W,
    const float* __restrict__ attS, const float* __restrict__ attD,
    float* __restrict__ h2, float* __restrict__ as2, float* __restrict__ ad2, int N)
{
    __shared__ unsigned short Wt[16 * 128];    // [n][k] swizzled, 4 KB
    __shared__ unsigned short xs[64 * 128];    // [m][k] swizzled, 16 KB
    const int t = threadIdx.x;
    const int lane = t & 63;
    const int wv = t >> 6;
    const int ln = lane & 15;
    const int lg = lane >> 4;
    const int r0 = blockIdx.x * 64;

    #pragma unroll
    for (int i = 0; i < 2; ++i) {
        int flat = i * 256 + t;        // 512 uint2 = 16 n x 32 k-groups
        int n = flat & 15;
        int k0 = (flat >> 4) * 4;
        float v0 = W[(size_t)(k0 + 0) * 16 + n];
        float v1 = W[(size_t)(k0 + 1) * 16 + n];
        float v2 = W[(size_t)(k0 + 2) * 16 + n];
        float v3 = W[(size_t)(k0 + 3) * 16 + n];
        uint2 pk;
        pk.x = bf16rne(v0) | (bf16rne(v1) << 16);
        pk.y = bf16rne(v2) | (bf16rne(v3) << 16);
        int byteo = n * 256 + ((k0 * 2) ^ ((n & 7) << 4));
        *(uint2*)((char*)Wt + byteo) = pk;
    }
    #pragma unroll
    for (int it = 0; it < 4; ++it) {
        int idx = t + it * 256;
        int m = idx >> 4, o = idx & 15;
        int rr = r0 + m;
        uint4 v = make_uint4(0, 0, 0, 0);
        if (rr < N) v = *(const uint4*)((const char*)(in + (size_t)rr * 128) + o * 16);
        int byteo = m * 256 + ((o * 16) ^ ((m & 7) << 4));
        *(uint4*)((char*)xs + byteo) = v;
    }
    __syncthreads();

    f32x4 acc = (f32x4)(0.f);
    #pragma unroll
    for (int kk = 0; kk < 4; ++kk) {
        int kb = (kk * 32 + lg * 8) * 2;
        int am = wv * 16 + ln;
        short8 a = *(const short8*)((char*)xs + am * 256 + (kb ^ ((am & 7) << 4)));
        short8 b = *(const short8*)((char*)Wt + ln * 256 + (kb ^ ((ln & 7) << 4)));
        acc = __builtin_amdgcn_mfma_f32_16x16x32_bf16(a, b, acc, 0, 0, 0);
    }

    float aSv = attS[ln], aDv = attD[ln];
    #pragma unroll
    for (int r = 0; r < 4; ++r) {
        int row = r0 + wv * 16 + lg * 4 + r;
        float s = acc[r] * aSv;
        float d = acc[r] * aDv;
        s += __shfl_xor(s, 1); s += __shfl_xor(s, 2); s += __shfl_xor(s, 4); s += __shfl_xor(s, 8);
        d += __shfl_xor(d, 1); d += __shfl_xor(d, 2); d += __shfl_xor(d, 4); d += __shfl_xor(d, 8);
        if (row < N) {
            h2[(size_t)row * 16 + ln] = acc[r];
            if (ln == 0) { as2[row] = s; ad2[row] = d; }
        }
    }
}

// ---------- layer-2 fused softmax+aggregate (recompute exp, no ex2 buffer) ----------
__global__ __launch_bounds__(256) void k_agg2(
    const float* __restrict__ h2, const float* __restrict__ as2,
    const float* __restrict__ ad2, const int* __restrict__ rowptr,
    const int* __restrict__ col, const float* __restrict__ b2,
    float* __restrict__ out, int N)
{
    int wid = (int)(((unsigned)blockIdx.x * blockDim.x + threadIdx.x) >> 6);
    if (wid >= N) return;
    int lane = threadIdx.x & 63;
    int start = rowptr[wid], end = rowptr[wid + 1];
    float adv = ad2[wid];

    float den = 0.f;
    for (int e = start + lane; e < end; e += 64)
        den += __expf(lrelu02(as2[col[e]] + adv));
    #pragma unroll
    for (int m = 32; m >= 1; m >>= 1) den += __shfl_xor(den, m);
    float rden = 1.f / den;

    int sub = lane >> 4, c = lane & 15;
    float acc = 0.f;
    for (int e0 = start + sub; e0 < end; e0 += 16) {
        int s[4];
        float av[4], km[4], hvv[4];
        #pragma unroll
        for (int j = 0; j < 4; ++j) {
            int ee = e0 + j * 4;
            bool ok = ee < end;
            int es = ok ? ee : e0;
            s[j]  = col[es];
            km[j] = ok ? 1.f : 0.f;
        }
        #pragma unroll
        for (int j = 0; j < 4; ++j)
            av[j] = as2[s[j]];
        #pragma unroll
        for (int j = 0; j < 4; ++j)
            hvv[j] = h2[(size_t)s[j] * 16 + c];
        #pragma unroll
        for (int j = 0; j < 4; ++j) {
            float coef = km[j] * __expf(lrelu02(av[j] + adv)) * rden;
            acc = fmaf(coef, hvv[j], acc);
        }
    }
    acc += __shfl_xor(acc, 16);
    acc += __shfl_xor(acc, 32);
    if (lane < 16) out[(size_t)wid * 16 + lane] = acc + b2[lane];
}

extern "C" void kernel_launch(void* const* d_in, const int* in_sizes, int n_in,
                              void* d_out, int out_size, void* d_ws, size_t ws_size,
                              hipStream_t stream)
{
    const float* x   = (const float*)d_in[0];
    const int*   ei  = (const int*)d_in[1];
    const float* W1  = (const float*)d_in[2];
    const float* aS1 = (const float*)d_in[3];
    const float* aD1 = (const float*)d_in[4];
    const float* b1  = (const float*)d_in[5];
    const float* W2  = (const float*)d_in[6];
    const float* aS2 = (const float*)d_in[7];
    const float* aD2 = (const float*)d_in[8];
    const float* b2  = (const float*)d_in[9];
    float* out = (float*)d_out;

    int N = in_sizes[0] / 128;
    int E = in_sizes[1] / 2;
    int ET = E + N;
    int nblk = (N + 2047) / 2048;
    int G1 = (N + 63) / 64;
    const int RB = 800;

    char* w = (char*)d_ws;
    auto alloc = [&](size_t bytes) -> void* {
        void* p = (void*)w;
        w += (bytes + 255) & ~(size_t)255;
        return p;
    };
    unsigned short* h1   = (unsigned short*)alloc((size_t)N * 128 * 2);
    unsigned short* out1 = (unsigned short*)alloc((size_t)N * 128 * 2);
    float* as1   = (float*)alloc((size_t)N * 4 * 4);
    float* ad1   = (float*)alloc((size_t)N * 4 * 4);
    float* h2    = (float*)alloc((size_t)N * 16 * 4);
    float* as2v  = (float*)alloc((size_t)N * 4);
    float* ad2v  = (float*)alloc((size_t)N * 4);
    int* deg     = (int*)alloc((size_t)N * 4);
    int* rowptr  = (int*)alloc((size_t)(N + 1) * 4);
    int* rank    = (int*)alloc((size_t)ET * 4);
    int* col     = (int*)alloc((size_t)ET * 4);
    int* bsum    = (int*)alloc(64 * 4);

    const int tb = 256;
    int n4 = (N + 3) / 4;
    k_zero  <<<(n4 + tb - 1) / tb, tb, 0, stream>>>((int4*)deg, n4);
    k_g1rank<<<RB + G1, tb, 0, stream>>>(x, W1, aS1, aD1, h1, as1, ad1,
                                         ei, deg, rank, E, N, RB);
    k_scan_local<<<nblk, tb, 0, stream>>>(deg, rowptr, bsum, N);
    k_scan_add  <<<nblk, tb, 0, stream>>>(rowptr, bsum, N, ET);
    k_fill2     <<<1024, tb, 0, stream>>>(ei, rank, rowptr, col, E, N);

    k_agg1 <<<(N + 3) / 4, tb, 0, stream>>>(h1, as1, ad1, rowptr, col, b1, out1, N);
    k_gemm2<<<G1, tb, 0, stream>>>(out1, W2, aS2, aD2, h2, as2v, ad2v, N);
    k_agg2 <<<(N + 3) / 4, tb, 0, stream>>>(h2, as2v, ad2v, rowptr, col, b2, out, N);
}